// Round 1
// baseline (185.566 us; speedup 1.0000x reference)
//
#include <hip/hip_runtime.h>

// Problem constants (fixed by reference)
#define B_ 8
#define N_ 8192
#define E_ 131072
#define D_ 128
#define M_ (B_ * N_)          // 65536 rows
#define SLOTS 64              // bucket capacity/node; P[Poisson(16)>64]~1e-21
#define WIN 256               // nodes per fill window (one fill block)
#define NWIN (N_ / WIN)       // 32 windows per batch -> 256 fill blocks
constexpr float INV_SQRT_N = 0.011048543456039806f;  // 1/sqrt(8192)
constexpr float LN_EPS_C = 1e-5f;

typedef __attribute__((ext_vector_type(8))) short bf16x8;   // 8 bf16 (4 VGPRs)
typedef __attribute__((ext_vector_type(4))) float f32x4;    // MFMA C/D
typedef __attribute__((ext_vector_type(4))) float f32x4v;   // clang vec (NT ld/st)
typedef __attribute__((ext_vector_type(4))) unsigned u32x4; // 16 B gather load

static __device__ __forceinline__ unsigned short f2bf(float f) {
  unsigned u = __float_as_uint(f);
  u += 0x7fffu + ((u >> 16) & 1u);
  return (unsigned short)(u >> 16);
}
static __device__ __forceinline__ float bflo(unsigned u) {
  return __uint_as_float(u << 16);
}
static __device__ __forceinline__ float bfhi(unsigned u) {
  return __uint_as_float(u & 0xffff0000u);
}
static __device__ __forceinline__ bf16x8 cvt8v(const f32x4v a, const f32x4v b) {
  bf16x8 r;
  r[0] = (short)f2bf(a.x); r[1] = (short)f2bf(a.y);
  r[2] = (short)f2bf(a.z); r[3] = (short)f2bf(a.w);
  r[4] = (short)f2bf(b.x); r[5] = (short)f2bf(b.y);
  r[6] = (short)f2bf(b.z); r[7] = (short)f2bf(b.w);
  return r;
}

// ---------------------------------------------------------------------------
// K1 fused: blocks 0..255 = MFMA GEMM (R9/R12 proven structure);
//           blocks 256..511 = PULL-BASED bucket fill (no global atomics).
//
// GEMM: 256 nodes/block; wave: hf=w&1 (feature half), ng=w>>1 (128 nodes);
// W-frags in registers once; strip loop 8 x [NT X-loads + 16 MFMA + 4 uint2].
// C/D (verified R6/R7): col=lane&15 -> node, row=(lane>>4)*4+reg -> feature.
//
// Fill (rewritten this round): the old version did 1M returning GLOBAL
// atomicAdds -> memory-side serialized RMW at ~14 Gops/s = ~70 us, with
// WRITE_SIZE inflated ~38 MB by 32 B atomic sector transactions. Now each
// fill block owns a 256-node window of one batch, scans that batch's full
// target list (1 MB, XCD-L2-resident via batch = blockIdx%8 swizzle), and
// allocates slots with returning LDS atomics on block-local counters.
// Bucket staged in 32 KB LDS, written back fully coalesced. cnt written
// directly (no memset kernel needed). Bucket/cnt format unchanged -> K2
// untouched.
// ---------------------------------------------------------------------------
__global__ __launch_bounds__(256, 4) void gemm_fill_kernel(
    const float* __restrict__ X, const float* __restrict__ W,
    const float* __restrict__ bias, const int* __restrict__ eidx,
    int* __restrict__ cnt, unsigned short* __restrict__ bucket,
    unsigned short* __restrict__ hb) {
  __shared__ unsigned cnt_l[WIN];                 // 1 KB
  __shared__ unsigned short bkt_l[WIN * SLOTS];   // 32 KB
  if (blockIdx.x < 256) {
    const int wave = threadIdx.x >> 6;
    const int lane = threadIdx.x & 63;
    const int m16 = lane & 15;
    const int q = lane >> 4;
    const int hf = wave & 1;     // feature half: feats [hf*64, +64)
    const int ng = wave >> 1;    // node group: nodes [ng*128, +128)

    bf16x8 wf[4][4];  // [kt4][t]
#pragma unroll
    for (int kt4 = 0; kt4 < 4; ++kt4) {
#pragma unroll
      for (int tt = 0; tt < 4; ++tt) {
        const float* wr = W + (size_t)(hf * 64 + tt * 16 + m16) * D_ +
                          kt4 * 32 + q * 8;
        wf[kt4][tt] = cvt8v(*(const f32x4v*)wr, *(const f32x4v*)(wr + 4));
      }
    }

    const int nbase0 = blockIdx.x * 256 + ng * 128;
#pragma unroll 2
    for (int s = 0; s < 8; ++s) {
      const int nbase = nbase0 + s * 16;
      const float* xrow = X + (size_t)(nbase + m16) * D_;

      f32x4 acc[4];
#pragma unroll
      for (int tt = 0; tt < 4; ++tt) acc[tt] = (f32x4){0.f, 0.f, 0.f, 0.f};

#pragma unroll
      for (int kt4 = 0; kt4 < 4; ++kt4) {
        const f32x4v xa = __builtin_nontemporal_load(
            (const f32x4v*)(xrow + kt4 * 32 + q * 8));
        const f32x4v xb = __builtin_nontemporal_load(
            (const f32x4v*)(xrow + kt4 * 32 + q * 8 + 4));
        const bf16x8 xf = cvt8v(xa, xb);
#pragma unroll
        for (int tt = 0; tt < 4; ++tt) {
          acc[tt] = __builtin_amdgcn_mfma_f32_16x16x32_bf16(wf[kt4][tt], xf,
                                                            acc[tt], 0, 0, 0);
        }
      }

      const size_t orow = (size_t)(nbase + m16) * D_;
#pragma unroll
      for (int tt = 0; tt < 4; ++tt) {
        const int f0 = hf * 64 + tt * 16 + q * 4;
        const float4 b4 = *(const float4*)&bias[f0];
        uint2 uu;
        uu.x = (unsigned)f2bf(acc[tt][0] + b4.x) |
               ((unsigned)f2bf(acc[tt][1] + b4.y) << 16);
        uu.y = (unsigned)f2bf(acc[tt][2] + b4.z) |
               ((unsigned)f2bf(acc[tt][3] + b4.w) << 16);
        *(uint2*)(hb + orow + f0) = uu;
      }
    }
  } else {
    // ---- pull-based fill: one block = one (batch, 256-node window) ----
    const int f = blockIdx.x - 256;      // 0..255
    const int batch = f & 7;             // XCD-locality: batch b -> XCD b
    const int w = f >> 3;                // window 0..31
    const int t = threadIdx.x;

    cnt_l[t] = 0u;
    __syncthreads();

    const int* __restrict__ srcp = eidx + batch * 2 * E_;
    const int* __restrict__ tgtp = srcp + E_;
    const int wbase = w * WIN;

    // Scan all E_ edges of this batch; 4 edges/thread/iter, coalesced int4
    // streams (L2-resident after warm). Per match: ds_add_rtn -> ds_write_b16.
#pragma unroll 2
    for (int it = 0; it < E_ / 1024; ++it) {
      const int e = it * 1024 + t * 4;
      const int4 tv = *(const int4*)&tgtp[e];
      const int4 sv = *(const int4*)&srcp[e];
      const unsigned l0 = (unsigned)(tv.x - wbase);
      const unsigned l1 = (unsigned)(tv.y - wbase);
      const unsigned l2 = (unsigned)(tv.z - wbase);
      const unsigned l3 = (unsigned)(tv.w - wbase);
      unsigned p0 = SLOTS, p1 = SLOTS, p2 = SLOTS, p3 = SLOTS;
      if (l0 < WIN) p0 = atomicAdd(&cnt_l[l0], 1u);
      if (l1 < WIN) p1 = atomicAdd(&cnt_l[l1], 1u);
      if (l2 < WIN) p2 = atomicAdd(&cnt_l[l2], 1u);
      if (l3 < WIN) p3 = atomicAdd(&cnt_l[l3], 1u);
      if (p0 < SLOTS) bkt_l[l0 * SLOTS + p0] = (unsigned short)sv.x;
      if (p1 < SLOTS) bkt_l[l1 * SLOTS + p1] = (unsigned short)sv.y;
      if (p2 < SLOTS) bkt_l[l2 * SLOTS + p2] = (unsigned short)sv.z;
      if (p3 < SLOTS) bkt_l[l3 * SLOTS + p3] = (unsigned short)sv.w;
    }
    __syncthreads();

    // Coalesced writeback: counts (1 KB) + bucket window (32 KB).
    const int nodebase = batch * N_ + wbase;
    cnt[nodebase + t] = (int)cnt_l[t];
    const u32x4* ls = (const u32x4*)bkt_l;
    u32x4* gd = (u32x4*)(bucket + (size_t)nodebase * SLOTS);
#pragma unroll
    for (int i = 0; i < (WIN * SLOTS * 2) / (16 * 256); ++i)
      gd[i * 256 + t] = ls[i * 256 + t];
  }
}

// ---------------------------------------------------------------------------
// K2: gather + residual + LN + ReLU + mask (R11's verified 16-lane-row
// structure on the direct bucket). 4 rows/wave, 16 lanes/row, lane owns
// 8 feats (one u32x4 = dwordx4 per gathered row -> 1 KB per wave-instr).
// Row's 64 index slots = one 128 B line; lane c holds slots 4c..4c+3 (uint2).
// 8 independent gathers in flight per row group. XCD swizzle + NT out stores.
// ---------------------------------------------------------------------------
__global__ __launch_bounds__(256, 8) void gather_finalize_kernel(
    const unsigned short* __restrict__ hb, const unsigned short* __restrict__ bucket,
    const int* __restrict__ cnt, const float* __restrict__ mask,
    const float* __restrict__ gamma, const float* __restrict__ beta,
    float* __restrict__ out) {
  const int bid = blockIdx.x;
  const int batch = bid & 7;             // XCD-locality heuristic
  const int wave = threadIdx.x >> 6;
  const int lane = threadIdx.x & 63;
  const int g = lane >> 4;               // row within wave's 4
  const int c = lane & 15;               // 16 lanes per row
  const int r = (bid >> 3) * 16 + wave * 4 + g;  // 0..8191 within batch
  const int row = batch * N_ + r;

  const u32x4* hub4 = (const u32x4*)hb + (size_t)batch * N_ * 16;

  // independent early loads
  const int deg = min(cnt[row], SLOTS);
  const uint2 su = *(const uint2*)&bucket[(size_t)row * SLOTS + c * 4];
  const u32x4 ur = hub4[r * 16 + c];
  const float m = mask[row];

  float a[8];
#pragma unroll
  for (int k = 0; k < 8; ++k) a[k] = 0.f;

  int jb = 0;
  for (; jb + 8 <= deg; jb += 8) {
    const int L = jb >> 2;
    const unsigned w0 = (unsigned)__shfl((int)su.x, L, 16);      // jb, jb+1
    const unsigned w1 = (unsigned)__shfl((int)su.y, L, 16);      // jb+2, jb+3
    const unsigned w2 = (unsigned)__shfl((int)su.x, L + 1, 16);  // jb+4, jb+5
    const unsigned w3 = (unsigned)__shfl((int)su.y, L + 1, 16);  // jb+6, jb+7
    const int idx[8] = {(int)(w0 & 0xffff), (int)(w0 >> 16),
                        (int)(w1 & 0xffff), (int)(w1 >> 16),
                        (int)(w2 & 0xffff), (int)(w2 >> 16),
                        (int)(w3 & 0xffff), (int)(w3 >> 16)};
    u32x4 v[8];
#pragma unroll
    for (int i = 0; i < 8; ++i) v[i] = hub4[idx[i] * 16 + c];
#pragma unroll
    for (int i = 0; i < 8; ++i) {
      a[0] += bflo(v[i].x); a[1] += bfhi(v[i].x);
      a[2] += bflo(v[i].y); a[3] += bfhi(v[i].y);
      a[4] += bflo(v[i].z); a[5] += bfhi(v[i].z);
      a[6] += bflo(v[i].w); a[7] += bfhi(v[i].w);
    }
  }
  for (; jb < deg; ++jb) {
    const int L = jb >> 2;
    const unsigned w = ((jb >> 1) & 1) ? (unsigned)__shfl((int)su.y, L, 16)
                                       : (unsigned)__shfl((int)su.x, L, 16);
    const int idx = (jb & 1) ? (int)(w >> 16) : (int)(w & 0xffff);
    const u32x4 v = hub4[idx * 16 + c];
    a[0] += bflo(v.x); a[1] += bfhi(v.x);
    a[2] += bflo(v.y); a[3] += bfhi(v.y);
    a[4] += bflo(v.z); a[5] += bfhi(v.z);
    a[6] += bflo(v.w); a[7] += bfhi(v.w);
  }

  float x[8];
  x[0] = bflo(ur.x) + a[0] * INV_SQRT_N;
  x[1] = bfhi(ur.x) + a[1] * INV_SQRT_N;
  x[2] = bflo(ur.y) + a[2] * INV_SQRT_N;
  x[3] = bfhi(ur.y) + a[3] * INV_SQRT_N;
  x[4] = bflo(ur.z) + a[4] * INV_SQRT_N;
  x[5] = bfhi(ur.z) + a[5] * INV_SQRT_N;
  x[6] = bflo(ur.w) + a[6] * INV_SQRT_N;
  x[7] = bfhi(ur.w) + a[7] * INV_SQRT_N;

  float s0 = 0.f, ss = 0.f;
#pragma unroll
  for (int k = 0; k < 8; ++k) {
    s0 += x[k];
    ss += x[k] * x[k];
  }
#pragma unroll
  for (int o = 8; o >= 1; o >>= 1) {
    s0 += __shfl_xor(s0, o, 16);
    ss += __shfl_xor(ss, o, 16);
  }
  const float mu = s0 * (1.f / 128.f);
  float var = ss * (1.f / 128.f) - mu * mu;
  var = var < 0.f ? 0.f : var;
  const float rstd = rsqrtf(var + LN_EPS_C);

  const f32x4v g0 = *((const f32x4v*)gamma + c * 2);
  const f32x4v g1 = *((const f32x4v*)gamma + c * 2 + 1);
  const f32x4v b0 = *((const f32x4v*)beta + c * 2);
  const f32x4v b1 = *((const f32x4v*)beta + c * 2 + 1);

  f32x4v o0, o1;
  o0.x = (x[0] - mu) * rstd * g0.x + b0.x;
  o0.y = (x[1] - mu) * rstd * g0.y + b0.y;
  o0.z = (x[2] - mu) * rstd * g0.z + b0.z;
  o0.w = (x[3] - mu) * rstd * g0.w + b0.w;
  o1.x = (x[4] - mu) * rstd * g1.x + b1.x;
  o1.y = (x[5] - mu) * rstd * g1.y + b1.y;
  o1.z = (x[6] - mu) * rstd * g1.z + b1.z;
  o1.w = (x[7] - mu) * rstd * g1.w + b1.w;
  o0.x = (o0.x > 0.f ? o0.x : 0.f) * m;
  o0.y = (o0.y > 0.f ? o0.y : 0.f) * m;
  o0.z = (o0.z > 0.f ? o0.z : 0.f) * m;
  o0.w = (o0.w > 0.f ? o0.w : 0.f) * m;
  o1.x = (o1.x > 0.f ? o1.x : 0.f) * m;
  o1.y = (o1.y > 0.f ? o1.y : 0.f) * m;
  o1.z = (o1.z > 0.f ? o1.z : 0.f) * m;
  o1.w = (o1.w > 0.f ? o1.w : 0.f) * m;

  f32x4v* op = (f32x4v*)out + (size_t)row * 32 + c * 2;
  __builtin_nontemporal_store(o0, op);
  __builtin_nontemporal_store(o1, op + 1);
}

// ---------------------------------------------------------------------------
extern "C" void kernel_launch(void* const* d_in, const int* in_sizes, int n_in,
                              void* d_out, int out_size, void* d_ws,
                              size_t ws_size, hipStream_t stream) {
  const float* X = (const float*)d_in[0];     // [B,N,128]
  const int* eidx = (const int*)d_in[1];      // [B,2,E]
  const float* mask = (const float*)d_in[2];  // [B,N]
  const float* W = (const float*)d_in[3];     // [128,128]
  const float* bias = (const float*)d_in[4];  // [128]
  const float* gamma = (const float*)d_in[5];
  const float* beta = (const float*)d_in[6];
  float* out = (float*)d_out;

  // workspace (~24.3 MB)
  unsigned short* hb = (unsigned short*)d_ws;             // 16 MB bf16
  unsigned short* bucket = hb + (size_t)M_ * D_;          // 8 MB (M_*64 ushort)
  int* cnt = (int*)(bucket + (size_t)M_ * SLOTS);         // 256 KB

  // no memset needed: every cnt entry is written by its owner fill block

  gemm_fill_kernel<<<256 + 256, 256, 0, stream>>>(X, W, bias, eidx, cnt,
                                                  bucket, hb);
  gather_finalize_kernel<<<M_ / 16, 256, 0, stream>>>(hb, bucket, cnt, mask,
                                                      gamma, beta, out);
}

// Round 2
// 184.312 us; speedup vs baseline: 1.0068x; 1.0068x over previous
//
#include <hip/hip_runtime.h>

// Problem constants (fixed by reference)
#define B_ 8
#define N_ 8192
#define E_ 131072
#define D_ 128
#define M_ (B_ * N_)          // 65536 rows
#define SLOTS 64              // bucket capacity/node; P[Poisson(16)>64]~1e-21
#define WIN 256               // nodes per fill window (one fill block)
#define QCAP 2048             // per-wave match queue (mean 1024, +32 sigma)
constexpr float INV_SQRT_N = 0.011048543456039806f;  // 1/sqrt(8192)
constexpr float LN_EPS_C = 1e-5f;

typedef __attribute__((ext_vector_type(8))) short bf16x8;   // 8 bf16 (4 VGPRs)
typedef __attribute__((ext_vector_type(4))) float f32x4;    // MFMA C/D
typedef __attribute__((ext_vector_type(4))) float f32x4v;   // clang vec (NT ld/st)
typedef __attribute__((ext_vector_type(4))) unsigned u32x4; // 16 B gather load

static __device__ __forceinline__ unsigned short f2bf(float f) {
  unsigned u = __float_as_uint(f);
  u += 0x7fffu + ((u >> 16) & 1u);
  return (unsigned short)(u >> 16);
}
static __device__ __forceinline__ float bflo(unsigned u) {
  return __uint_as_float(u << 16);
}
static __device__ __forceinline__ float bfhi(unsigned u) {
  return __uint_as_float(u & 0xffff0000u);
}
static __device__ __forceinline__ bf16x8 cvt8v(const f32x4v a, const f32x4v b) {
  bf16x8 r;
  r[0] = (short)f2bf(a.x); r[1] = (short)f2bf(a.y);
  r[2] = (short)f2bf(a.z); r[3] = (short)f2bf(a.w);
  r[4] = (short)f2bf(b.x); r[5] = (short)f2bf(b.y);
  r[6] = (short)f2bf(b.z); r[7] = (short)f2bf(b.w);
  return r;
}
// count of set bits in m strictly below this lane
static __device__ __forceinline__ unsigned lanepos(unsigned long long m) {
  return __builtin_amdgcn_mbcnt_hi(
      (unsigned)(m >> 32), __builtin_amdgcn_mbcnt_lo((unsigned)m, 0u));
}

// ---------------------------------------------------------------------------
// K1 fused: blocks 0..255 = MFMA GEMM (proven structure);
//           blocks 256..511 = pull-based bucket fill, ballot-compacted.
//
// Fill post-mortem R1: in-loop predicated ds_add_rtn chains serialized
// (~600cy/iter x 128 iters, 1 wave/SIMD, no hiding) -> 93us. Now the scan
// loop has NO LDS-returning ops: matches (expected 8/256 edges per wave-iter)
// are ballot-compacted into a per-wave LDS queue; the queue cursor is an
// SGPR bumped by popc(ballot). Slot allocation + lazy src fetch happen in a
// short post-loop insert phase with 2 independent chains in flight.
// Bucket staged in 32 KB LDS, written back fully coalesced; cnt written
// directly. Bucket/cnt format unchanged -> K2 untouched.
// ---------------------------------------------------------------------------
__global__ __launch_bounds__(256, 4) void gemm_fill_kernel(
    const float* __restrict__ X, const float* __restrict__ W,
    const float* __restrict__ bias, const int* __restrict__ eidx,
    int* __restrict__ cnt, unsigned short* __restrict__ bucket,
    unsigned short* __restrict__ hb) {
  __shared__ unsigned cnt_l[WIN];                 // 1 KB
  __shared__ unsigned short bkt_l[WIN * SLOTS];   // 32 KB
  __shared__ unsigned q_l[4 * QCAP];              // 32 KB (per-wave queues)
  if (blockIdx.x < 256) {
    const int wave = threadIdx.x >> 6;
    const int lane = threadIdx.x & 63;
    const int m16 = lane & 15;
    const int q = lane >> 4;
    const int hf = wave & 1;     // feature half: feats [hf*64, +64)
    const int ng = wave >> 1;    // node group: nodes [ng*128, +128)

    bf16x8 wf[4][4];  // [kt4][t]
#pragma unroll
    for (int kt4 = 0; kt4 < 4; ++kt4) {
#pragma unroll
      for (int tt = 0; tt < 4; ++tt) {
        const float* wr = W + (size_t)(hf * 64 + tt * 16 + m16) * D_ +
                          kt4 * 32 + q * 8;
        wf[kt4][tt] = cvt8v(*(const f32x4v*)wr, *(const f32x4v*)(wr + 4));
      }
    }

    const int nbase0 = blockIdx.x * 256 + ng * 128;
#pragma unroll 2
    for (int s = 0; s < 8; ++s) {
      const int nbase = nbase0 + s * 16;
      const float* xrow = X + (size_t)(nbase + m16) * D_;

      f32x4 acc[4];
#pragma unroll
      for (int tt = 0; tt < 4; ++tt) acc[tt] = (f32x4){0.f, 0.f, 0.f, 0.f};

#pragma unroll
      for (int kt4 = 0; kt4 < 4; ++kt4) {
        const f32x4v xa = __builtin_nontemporal_load(
            (const f32x4v*)(xrow + kt4 * 32 + q * 8));
        const f32x4v xb = __builtin_nontemporal_load(
            (const f32x4v*)(xrow + kt4 * 32 + q * 8 + 4));
        const bf16x8 xf = cvt8v(xa, xb);
#pragma unroll
        for (int tt = 0; tt < 4; ++tt) {
          acc[tt] = __builtin_amdgcn_mfma_f32_16x16x32_bf16(wf[kt4][tt], xf,
                                                            acc[tt], 0, 0, 0);
        }
      }

      const size_t orow = (size_t)(nbase + m16) * D_;
#pragma unroll
      for (int tt = 0; tt < 4; ++tt) {
        const int f0 = hf * 64 + tt * 16 + q * 4;
        const float4 b4 = *(const float4*)&bias[f0];
        uint2 uu;
        uu.x = (unsigned)f2bf(acc[tt][0] + b4.x) |
               ((unsigned)f2bf(acc[tt][1] + b4.y) << 16);
        uu.y = (unsigned)f2bf(acc[tt][2] + b4.z) |
               ((unsigned)f2bf(acc[tt][3] + b4.w) << 16);
        *(uint2*)(hb + orow + f0) = uu;
      }
    }
  } else {
    // ---- pull-based fill: one block = one (batch, 256-node window) ----
    const int f = blockIdx.x - 256;      // 0..255
    const int batch = f & 7;             // XCD-locality: batch b -> XCD b
    const int w = f >> 3;                // window 0..31
    const int t = threadIdx.x;
    const int wave = t >> 6;
    const int lane = t & 63;

    cnt_l[t] = 0u;
    __syncthreads();

    const int* __restrict__ srcp = eidx + batch * 2 * E_;
    const int* __restrict__ tgtp = srcp + E_;
    const int wbase = w * WIN;

    unsigned* __restrict__ qw = q_l + wave * QCAP;
    unsigned qn = 0;  // wave-uniform (updated by popc of ballot)

    // Phase A: stream targets only; ballot-compact matches into wave queue.
    // Entry = (local_node << 17) | edge_idx  (local<256 -> 8b, e<2^17).
    // No LDS-returning ops in this loop -> no serial chains.
#pragma unroll 2
    for (int it = 0; it < E_ / 1024; ++it) {
      const int e = it * 1024 + t * 4;
      const int4 tv = *(const int4*)&tgtp[e];
      const unsigned l0 = (unsigned)(tv.x - wbase);
      const unsigned l1 = (unsigned)(tv.y - wbase);
      const unsigned l2 = (unsigned)(tv.z - wbase);
      const unsigned l3 = (unsigned)(tv.w - wbase);
      {
        const bool m = l0 < WIN;
        const unsigned long long bal = __ballot(m);
        if (m) qw[qn + lanepos(bal)] = (l0 << 17) | (unsigned)e;
        qn += (unsigned)__popcll(bal);
      }
      {
        const bool m = l1 < WIN;
        const unsigned long long bal = __ballot(m);
        if (m) qw[qn + lanepos(bal)] = (l1 << 17) | (unsigned)(e + 1);
        qn += (unsigned)__popcll(bal);
      }
      {
        const bool m = l2 < WIN;
        const unsigned long long bal = __ballot(m);
        if (m) qw[qn + lanepos(bal)] = (l2 << 17) | (unsigned)(e + 2);
        qn += (unsigned)__popcll(bal);
      }
      {
        const bool m = l3 < WIN;
        const unsigned long long bal = __ballot(m);
        if (m) qw[qn + lanepos(bal)] = (l3 << 17) | (unsigned)(e + 3);
        qn += (unsigned)__popcll(bal);
      }
    }

    // Phase B: insert own wave's queue entries. Lazy src fetch (L2-hot),
    // LDS atomic slot alloc, 2 independent chains in flight.
    unsigned j = lane;
    for (; j + 64 < qn; j += 128) {
      const unsigned v0 = qw[j];
      const unsigned v1 = qw[j + 64];
      const unsigned short s0 = (unsigned short)srcp[v0 & 0x1FFFFu];
      const unsigned short s1 = (unsigned short)srcp[v1 & 0x1FFFFu];
      const unsigned p0 = atomicAdd(&cnt_l[v0 >> 17], 1u);
      const unsigned p1 = atomicAdd(&cnt_l[v1 >> 17], 1u);
      if (p0 < SLOTS) bkt_l[(v0 >> 17) * SLOTS + p0] = s0;
      if (p1 < SLOTS) bkt_l[(v1 >> 17) * SLOTS + p1] = s1;
    }
    if (j < qn) {
      const unsigned v = qw[j];
      const unsigned short s = (unsigned short)srcp[v & 0x1FFFFu];
      const unsigned p = atomicAdd(&cnt_l[v >> 17], 1u);
      if (p < SLOTS) bkt_l[(v >> 17) * SLOTS + p] = s;
    }
    __syncthreads();

    // Coalesced writeback: counts (1 KB) + bucket window (32 KB).
    const int nodebase = batch * N_ + wbase;
    cnt[nodebase + t] = (int)cnt_l[t];
    const u32x4* ls = (const u32x4*)bkt_l;
    u32x4* gd = (u32x4*)(bucket + (size_t)nodebase * SLOTS);
#pragma unroll
    for (int i = 0; i < (WIN * SLOTS * 2) / (16 * 256); ++i)
      gd[i * 256 + t] = ls[i * 256 + t];
  }
}

// ---------------------------------------------------------------------------
// K2: gather + residual + LN + ReLU + mask (verified 16-lane-row structure).
// 4 rows/wave, 16 lanes/row, lane owns 8 feats (one u32x4 per gathered row).
// Row's 64 index slots = one 128 B line; lane c holds slots 4c..4c+3 (uint2).
// 8 independent gathers in flight per row group. XCD swizzle + NT out stores.
// ---------------------------------------------------------------------------
__global__ __launch_bounds__(256, 8) void gather_finalize_kernel(
    const unsigned short* __restrict__ hb, const unsigned short* __restrict__ bucket,
    const int* __restrict__ cnt, const float* __restrict__ mask,
    const float* __restrict__ gamma, const float* __restrict__ beta,
    float* __restrict__ out) {
  const int bid = blockIdx.x;
  const int batch = bid & 7;             // XCD-locality heuristic
  const int wave = threadIdx.x >> 6;
  const int lane = threadIdx.x & 63;
  const int g = lane >> 4;               // row within wave's 4
  const int c = lane & 15;               // 16 lanes per row
  const int r = (bid >> 3) * 16 + wave * 4 + g;  // 0..8191 within batch
  const int row = batch * N_ + r;

  const u32x4* hub4 = (const u32x4*)hb + (size_t)batch * N_ * 16;

  // independent early loads
  const int deg = min(cnt[row], SLOTS);
  const uint2 su = *(const uint2*)&bucket[(size_t)row * SLOTS + c * 4];
  const u32x4 ur = hub4[r * 16 + c];
  const float m = mask[row];

  float a[8];
#pragma unroll
  for (int k = 0; k < 8; ++k) a[k] = 0.f;

  int jb = 0;
  for (; jb + 8 <= deg; jb += 8) {
    const int L = jb >> 2;
    const unsigned w0 = (unsigned)__shfl((int)su.x, L, 16);      // jb, jb+1
    const unsigned w1 = (unsigned)__shfl((int)su.y, L, 16);      // jb+2, jb+3
    const unsigned w2 = (unsigned)__shfl((int)su.x, L + 1, 16);  // jb+4, jb+5
    const unsigned w3 = (unsigned)__shfl((int)su.y, L + 1, 16);  // jb+6, jb+7
    const int idx[8] = {(int)(w0 & 0xffff), (int)(w0 >> 16),
                        (int)(w1 & 0xffff), (int)(w1 >> 16),
                        (int)(w2 & 0xffff), (int)(w2 >> 16),
                        (int)(w3 & 0xffff), (int)(w3 >> 16)};
    u32x4 v[8];
#pragma unroll
    for (int i = 0; i < 8; ++i) v[i] = hub4[idx[i] * 16 + c];
#pragma unroll
    for (int i = 0; i < 8; ++i) {
      a[0] += bflo(v[i].x); a[1] += bfhi(v[i].x);
      a[2] += bflo(v[i].y); a[3] += bfhi(v[i].y);
      a[4] += bflo(v[i].z); a[5] += bfhi(v[i].z);
      a[6] += bflo(v[i].w); a[7] += bfhi(v[i].w);
    }
  }
  for (; jb < deg; ++jb) {
    const int L = jb >> 2;
    const unsigned w = ((jb >> 1) & 1) ? (unsigned)__shfl((int)su.y, L, 16)
                                       : (unsigned)__shfl((int)su.x, L, 16);
    const int idx = (jb & 1) ? (int)(w >> 16) : (int)(w & 0xffff);
    const u32x4 v = hub4[idx * 16 + c];
    a[0] += bflo(v.x); a[1] += bfhi(v.x);
    a[2] += bflo(v.y); a[3] += bfhi(v.y);
    a[4] += bflo(v.z); a[5] += bfhi(v.z);
    a[6] += bflo(v.w); a[7] += bfhi(v.w);
  }

  float x[8];
  x[0] = bflo(ur.x) + a[0] * INV_SQRT_N;
  x[1] = bfhi(ur.x) + a[1] * INV_SQRT_N;
  x[2] = bflo(ur.y) + a[2] * INV_SQRT_N;
  x[3] = bfhi(ur.y) + a[3] * INV_SQRT_N;
  x[4] = bflo(ur.z) + a[4] * INV_SQRT_N;
  x[5] = bfhi(ur.z) + a[5] * INV_SQRT_N;
  x[6] = bflo(ur.w) + a[6] * INV_SQRT_N;
  x[7] = bfhi(ur.w) + a[7] * INV_SQRT_N;

  float s0 = 0.f, ss = 0.f;
#pragma unroll
  for (int k = 0; k < 8; ++k) {
    s0 += x[k];
    ss += x[k] * x[k];
  }
#pragma unroll
  for (int o = 8; o >= 1; o >>= 1) {
    s0 += __shfl_xor(s0, o, 16);
    ss += __shfl_xor(ss, o, 16);
  }
  const float mu = s0 * (1.f / 128.f);
  float var = ss * (1.f / 128.f) - mu * mu;
  var = var < 0.f ? 0.f : var;
  const float rstd = rsqrtf(var + LN_EPS_C);

  const f32x4v g0 = *((const f32x4v*)gamma + c * 2);
  const f32x4v g1 = *((const f32x4v*)gamma + c * 2 + 1);
  const f32x4v b0 = *((const f32x4v*)beta + c * 2);
  const f32x4v b1 = *((const f32x4v*)beta + c * 2 + 1);

  f32x4v o0, o1;
  o0.x = (x[0] - mu) * rstd * g0.x + b0.x;
  o0.y = (x[1] - mu) * rstd * g0.y + b0.y;
  o0.z = (x[2] - mu) * rstd * g0.z + b0.z;
  o0.w = (x[3] - mu) * rstd * g0.w + b0.w;
  o1.x = (x[4] - mu) * rstd * g1.x + b1.x;
  o1.y = (x[5] - mu) * rstd * g1.y + b1.y;
  o1.z = (x[6] - mu) * rstd * g1.z + b1.z;
  o1.w = (x[7] - mu) * rstd * g1.w + b1.w;
  o0.x = (o0.x > 0.f ? o0.x : 0.f) * m;
  o0.y = (o0.y > 0.f ? o0.y : 0.f) * m;
  o0.z = (o0.z > 0.f ? o0.z : 0.f) * m;
  o0.w = (o0.w > 0.f ? o0.w : 0.f) * m;
  o1.x = (o1.x > 0.f ? o1.x : 0.f) * m;
  o1.y = (o1.y > 0.f ? o1.y : 0.f) * m;
  o1.z = (o1.z > 0.f ? o1.z : 0.f) * m;
  o1.w = (o1.w > 0.f ? o1.w : 0.f) * m;

  f32x4v* op = (f32x4v*)out + (size_t)row * 32 + c * 2;
  __builtin_nontemporal_store(o0, op);
  __builtin_nontemporal_store(o1, op + 1);
}

// ---------------------------------------------------------------------------
extern "C" void kernel_launch(void* const* d_in, const int* in_sizes, int n_in,
                              void* d_out, int out_size, void* d_ws,
                              size_t ws_size, hipStream_t stream) {
  const float* X = (const float*)d_in[0];     // [B,N,128]
  const int* eidx = (const int*)d_in[1];      // [B,2,E]
  const float* mask = (const float*)d_in[2];  // [B,N]
  const float* W = (const float*)d_in[3];     // [128,128]
  const float* bias = (const float*)d_in[4];  // [128]
  const float* gamma = (const float*)d_in[5];
  const float* beta = (const float*)d_in[6];
  float* out = (float*)d_out;

  // workspace (~24.3 MB)
  unsigned short* hb = (unsigned short*)d_ws;             // 16 MB bf16
  unsigned short* bucket = hb + (size_t)M_ * D_;          // 8 MB (M_*64 ushort)
  int* cnt = (int*)(bucket + (size_t)M_ * SLOTS);         // 256 KB

  // no memset needed: every cnt entry is written by its owner fill block

  gemm_fill_kernel<<<256 + 256, 256, 0, stream>>>(X, W, bias, eidx, cnt,
                                                  bucket, hb);
  gather_finalize_kernel<<<M_ / 16, 256, 0, stream>>>(hb, bucket, cnt, mask,
                                                      gamma, beta, out);
}

// Round 3
// 166.366 us; speedup vs baseline: 1.1154x; 1.1079x over previous
//
#include <hip/hip_runtime.h>

// Problem constants (fixed by reference)
#define B_ 8
#define N_ 8192
#define E_ 131072
#define D_ 128
#define M_ (B_ * N_)          // 65536 rows
#define SLOTS 64              // bucket capacity/node; P[Poisson(16)>64]~1e-21
#define FWIN 512              // nodes per fill window (one 1024-thr fill block)
constexpr float INV_SQRT_N = 0.011048543456039806f;  // 1/sqrt(8192)
constexpr float LN_EPS_C = 1e-5f;

typedef __attribute__((ext_vector_type(8))) short bf16x8;   // 8 bf16 (4 VGPRs)
typedef __attribute__((ext_vector_type(4))) float f32x4;    // MFMA C/D
typedef __attribute__((ext_vector_type(4))) float f32x4v;   // clang vec (NT ld/st)
typedef __attribute__((ext_vector_type(4))) unsigned u32x4; // 16 B gather load

static __device__ __forceinline__ unsigned short f2bf(float f) {
  unsigned u = __float_as_uint(f);
  u += 0x7fffu + ((u >> 16) & 1u);
  return (unsigned short)(u >> 16);
}
static __device__ __forceinline__ float bflo(unsigned u) {
  return __uint_as_float(u << 16);
}
static __device__ __forceinline__ float bfhi(unsigned u) {
  return __uint_as_float(u & 0xffff0000u);
}
static __device__ __forceinline__ bf16x8 cvt8v(const f32x4v a, const f32x4v b) {
  bf16x8 r;
  r[0] = (short)f2bf(a.x); r[1] = (short)f2bf(a.y);
  r[2] = (short)f2bf(a.z); r[3] = (short)f2bf(a.w);
  r[4] = (short)f2bf(b.x); r[5] = (short)f2bf(b.y);
  r[6] = (short)f2bf(b.z); r[7] = (short)f2bf(b.w);
  return r;
}

// ---------------------------------------------------------------------------
// K1 fused, 1024-thread blocks, exactly 256 blocks = 1 block/CU:
//   blocks 0..127   = MFMA GEMM, 512 nodes/block (16 waves; wave: hf=w&1
//                     feature half, ng=w>>1 node group of 64; 4 strips of 16).
//   blocks 128..255 = pull-based fill, 512-node window/block, 16 waves.
//
// Fill post-mortem R1/R2: two different inner loops both ran ~92us at
// 1 wave/SIMD -> the scan was pure exposed global-load latency (128 serial
// iters/wave, nothing to hide with). Fix: 16 waves/block (4/SIMD), 8 edges/
// thread/iter -> 16 iterations, explicit next-iteration prefetch (4 int4
// loads issued before current iter's LDS atomics). Direct LDS-atomic insert
// (4 atomics issued, then 4 bucket writes). Bucket staged in 64 KB LDS,
// coalesced writeback; cnt written directly. Format unchanged -> K2 as-is.
// Fill batch = (blockIdx-128)&7 == blockIdx%8 -> batch's 1 MB edge slice
// stays XCD-L2-resident.
// ---------------------------------------------------------------------------
__global__ __launch_bounds__(1024, 4) void gemm_fill_kernel(
    const float* __restrict__ X, const float* __restrict__ W,
    const float* __restrict__ bias, const int* __restrict__ eidx,
    int* __restrict__ cnt, unsigned short* __restrict__ bucket,
    unsigned short* __restrict__ hb) {
  __shared__ unsigned cnt_l[FWIN];                 // 2 KB
  __shared__ unsigned short bkt_l[FWIN * SLOTS];   // 64 KB
  if (blockIdx.x < 128) {
    const int wave = threadIdx.x >> 6;   // 0..15
    const int lane = threadIdx.x & 63;
    const int m16 = lane & 15;
    const int q = lane >> 4;
    const int hf = wave & 1;     // feature half: feats [hf*64, +64)
    const int ng = wave >> 1;    // node group: nodes [ng*64, +64)

    bf16x8 wf[4][4];  // [kt4][t]
#pragma unroll
    for (int kt4 = 0; kt4 < 4; ++kt4) {
#pragma unroll
      for (int tt = 0; tt < 4; ++tt) {
        const float* wr = W + (size_t)(hf * 64 + tt * 16 + m16) * D_ +
                          kt4 * 32 + q * 8;
        wf[kt4][tt] = cvt8v(*(const f32x4v*)wr, *(const f32x4v*)(wr + 4));
      }
    }

    const int nbase0 = blockIdx.x * 512 + ng * 64;
#pragma unroll 2
    for (int s = 0; s < 4; ++s) {
      const int nbase = nbase0 + s * 16;
      const float* xrow = X + (size_t)(nbase + m16) * D_;

      f32x4 acc[4];
#pragma unroll
      for (int tt = 0; tt < 4; ++tt) acc[tt] = (f32x4){0.f, 0.f, 0.f, 0.f};

#pragma unroll
      for (int kt4 = 0; kt4 < 4; ++kt4) {
        const f32x4v xa = __builtin_nontemporal_load(
            (const f32x4v*)(xrow + kt4 * 32 + q * 8));
        const f32x4v xb = __builtin_nontemporal_load(
            (const f32x4v*)(xrow + kt4 * 32 + q * 8 + 4));
        const bf16x8 xf = cvt8v(xa, xb);
#pragma unroll
        for (int tt = 0; tt < 4; ++tt) {
          acc[tt] = __builtin_amdgcn_mfma_f32_16x16x32_bf16(wf[kt4][tt], xf,
                                                            acc[tt], 0, 0, 0);
        }
      }

      const size_t orow = (size_t)(nbase + m16) * D_;
#pragma unroll
      for (int tt = 0; tt < 4; ++tt) {
        const int f0 = hf * 64 + tt * 16 + q * 4;
        const float4 b4 = *(const float4*)&bias[f0];
        uint2 uu;
        uu.x = (unsigned)f2bf(acc[tt][0] + b4.x) |
               ((unsigned)f2bf(acc[tt][1] + b4.y) << 16);
        uu.y = (unsigned)f2bf(acc[tt][2] + b4.z) |
               ((unsigned)f2bf(acc[tt][3] + b4.w) << 16);
        *(uint2*)(hb + orow + f0) = uu;
      }
    }
  } else {
    // ---- pull-based fill: one block = one (batch, 512-node window) ----
    const int f = blockIdx.x - 128;      // 0..127
    const int batch = f & 7;             // == blockIdx%8 -> XCD-local edges
    const int w = f >> 3;                // window 0..15
    const int t = threadIdx.x;           // 0..1023
    const int wbase = w * FWIN;

    if (t < FWIN) cnt_l[t] = 0u;
    __syncthreads();

    const int* __restrict__ srcp = eidx + batch * 2 * E_;
    const int* __restrict__ tgtp = srcp + E_;

// 4 edges: issue the (predicated) LDS atomics first, then the bucket writes.
#define PROC4(tv, sv)                                                   \
  {                                                                     \
    const unsigned l0 = (unsigned)(tv.x - wbase);                       \
    const unsigned l1 = (unsigned)(tv.y - wbase);                       \
    const unsigned l2 = (unsigned)(tv.z - wbase);                       \
    const unsigned l3 = (unsigned)(tv.w - wbase);                       \
    unsigned p0 = 0xffffu, p1 = 0xffffu, p2 = 0xffffu, p3 = 0xffffu;    \
    if (l0 < FWIN) p0 = atomicAdd(&cnt_l[l0], 1u);                      \
    if (l1 < FWIN) p1 = atomicAdd(&cnt_l[l1], 1u);                      \
    if (l2 < FWIN) p2 = atomicAdd(&cnt_l[l2], 1u);                      \
    if (l3 < FWIN) p3 = atomicAdd(&cnt_l[l3], 1u);                      \
    if (p0 < SLOTS) bkt_l[l0 * SLOTS + p0] = (unsigned short)sv.x;      \
    if (p1 < SLOTS) bkt_l[l1 * SLOTS + p1] = (unsigned short)sv.y;      \
    if (p2 < SLOTS) bkt_l[l2 * SLOTS + p2] = (unsigned short)sv.z;      \
    if (p3 < SLOTS) bkt_l[l3 * SLOTS + p3] = (unsigned short)sv.w;      \
  }

    // 8 edges/thread/iter, 16 iters; next iteration's 4 loads issued before
    // this iteration's LDS work (one-deep software pipeline).
    int e = t * 8;
    int4 ct0 = *(const int4*)(tgtp + e);
    int4 ct1 = *(const int4*)(tgtp + e + 4);
    int4 cs0 = *(const int4*)(srcp + e);
    int4 cs1 = *(const int4*)(srcp + e + 4);
#pragma unroll 1
    for (int it = 0; it < 15; ++it) {
      const int en = e + 8192;
      const int4 nt0 = *(const int4*)(tgtp + en);
      const int4 nt1 = *(const int4*)(tgtp + en + 4);
      const int4 ns0 = *(const int4*)(srcp + en);
      const int4 ns1 = *(const int4*)(srcp + en + 4);
      PROC4(ct0, cs0);
      PROC4(ct1, cs1);
      ct0 = nt0; ct1 = nt1; cs0 = ns0; cs1 = ns1;
      e = en;
    }
    PROC4(ct0, cs0);
    PROC4(ct1, cs1);
#undef PROC4
    __syncthreads();

    // Coalesced writeback: counts (2 KB) + bucket window (64 KB).
    const int nodebase = batch * N_ + wbase;
    if (t < FWIN) cnt[nodebase + t] = (int)cnt_l[t];
    const u32x4* ls = (const u32x4*)bkt_l;
    u32x4* gd = (u32x4*)(bucket + (size_t)nodebase * SLOTS);
#pragma unroll
    for (int i = 0; i < (FWIN * SLOTS * 2) / (16 * 1024); ++i)
      gd[i * 1024 + t] = ls[i * 1024 + t];
  }
}

// ---------------------------------------------------------------------------
// K2: gather + residual + LN + ReLU + mask (verified 16-lane-row structure).
// 4 rows/wave, 16 lanes/row, lane owns 8 feats (one u32x4 per gathered row).
// Row's 64 index slots = one 128 B line; lane c holds slots 4c..4c+3 (uint2).
// 8 independent gathers in flight per row group. XCD swizzle + NT out stores.
// ---------------------------------------------------------------------------
__global__ __launch_bounds__(256, 8) void gather_finalize_kernel(
    const unsigned short* __restrict__ hb, const unsigned short* __restrict__ bucket,
    const int* __restrict__ cnt, const float* __restrict__ mask,
    const float* __restrict__ gamma, const float* __restrict__ beta,
    float* __restrict__ out) {
  const int bid = blockIdx.x;
  const int batch = bid & 7;             // XCD-locality heuristic
  const int wave = threadIdx.x >> 6;
  const int lane = threadIdx.x & 63;
  const int g = lane >> 4;               // row within wave's 4
  const int c = lane & 15;               // 16 lanes per row
  const int r = (bid >> 3) * 16 + wave * 4 + g;  // 0..8191 within batch
  const int row = batch * N_ + r;

  const u32x4* hub4 = (const u32x4*)hb + (size_t)batch * N_ * 16;

  // independent early loads
  const int deg = min(cnt[row], SLOTS);
  const uint2 su = *(const uint2*)&bucket[(size_t)row * SLOTS + c * 4];
  const u32x4 ur = hub4[r * 16 + c];
  const float m = mask[row];

  float a[8];
#pragma unroll
  for (int k = 0; k < 8; ++k) a[k] = 0.f;

  int jb = 0;
  for (; jb + 8 <= deg; jb += 8) {
    const int L = jb >> 2;
    const unsigned w0 = (unsigned)__shfl((int)su.x, L, 16);      // jb, jb+1
    const unsigned w1 = (unsigned)__shfl((int)su.y, L, 16);      // jb+2, jb+3
    const unsigned w2 = (unsigned)__shfl((int)su.x, L + 1, 16);  // jb+4, jb+5
    const unsigned w3 = (unsigned)__shfl((int)su.y, L + 1, 16);  // jb+6, jb+7
    const int idx[8] = {(int)(w0 & 0xffff), (int)(w0 >> 16),
                        (int)(w1 & 0xffff), (int)(w1 >> 16),
                        (int)(w2 & 0xffff), (int)(w2 >> 16),
                        (int)(w3 & 0xffff), (int)(w3 >> 16)};
    u32x4 v[8];
#pragma unroll
    for (int i = 0; i < 8; ++i) v[i] = hub4[idx[i] * 16 + c];
#pragma unroll
    for (int i = 0; i < 8; ++i) {
      a[0] += bflo(v[i].x); a[1] += bfhi(v[i].x);
      a[2] += bflo(v[i].y); a[3] += bfhi(v[i].y);
      a[4] += bflo(v[i].z); a[5] += bfhi(v[i].z);
      a[6] += bflo(v[i].w); a[7] += bfhi(v[i].w);
    }
  }
  for (; jb < deg; ++jb) {
    const int L = jb >> 2;
    const unsigned w = ((jb >> 1) & 1) ? (unsigned)__shfl((int)su.y, L, 16)
                                       : (unsigned)__shfl((int)su.x, L, 16);
    const int idx = (jb & 1) ? (int)(w >> 16) : (int)(w & 0xffff);
    const u32x4 v = hub4[idx * 16 + c];
    a[0] += bflo(v.x); a[1] += bfhi(v.x);
    a[2] += bflo(v.y); a[3] += bfhi(v.y);
    a[4] += bflo(v.z); a[5] += bfhi(v.z);
    a[6] += bflo(v.w); a[7] += bfhi(v.w);
  }

  float x[8];
  x[0] = bflo(ur.x) + a[0] * INV_SQRT_N;
  x[1] = bfhi(ur.x) + a[1] * INV_SQRT_N;
  x[2] = bflo(ur.y) + a[2] * INV_SQRT_N;
  x[3] = bfhi(ur.y) + a[3] * INV_SQRT_N;
  x[4] = bflo(ur.z) + a[4] * INV_SQRT_N;
  x[5] = bfhi(ur.z) + a[5] * INV_SQRT_N;
  x[6] = bflo(ur.w) + a[6] * INV_SQRT_N;
  x[7] = bfhi(ur.w) + a[7] * INV_SQRT_N;

  float s0 = 0.f, ss = 0.f;
#pragma unroll
  for (int k = 0; k < 8; ++k) {
    s0 += x[k];
    ss += x[k] * x[k];
  }
#pragma unroll
  for (int o = 8; o >= 1; o >>= 1) {
    s0 += __shfl_xor(s0, o, 16);
    ss += __shfl_xor(ss, o, 16);
  }
  const float mu = s0 * (1.f / 128.f);
  float var = ss * (1.f / 128.f) - mu * mu;
  var = var < 0.f ? 0.f : var;
  const float rstd = rsqrtf(var + LN_EPS_C);

  const f32x4v g0 = *((const f32x4v*)gamma + c * 2);
  const f32x4v g1 = *((const f32x4v*)gamma + c * 2 + 1);
  const f32x4v b0 = *((const f32x4v*)beta + c * 2);
  const f32x4v b1 = *((const f32x4v*)beta + c * 2 + 1);

  f32x4v o0, o1;
  o0.x = (x[0] - mu) * rstd * g0.x + b0.x;
  o0.y = (x[1] - mu) * rstd * g0.y + b0.y;
  o0.z = (x[2] - mu) * rstd * g0.z + b0.z;
  o0.w = (x[3] - mu) * rstd * g0.w + b0.w;
  o1.x = (x[4] - mu) * rstd * g1.x + b1.x;
  o1.y = (x[5] - mu) * rstd * g1.y + b1.y;
  o1.z = (x[6] - mu) * rstd * g1.z + b1.z;
  o1.w = (x[7] - mu) * rstd * g1.w + b1.w;
  o0.x = (o0.x > 0.f ? o0.x : 0.f) * m;
  o0.y = (o0.y > 0.f ? o0.y : 0.f) * m;
  o0.z = (o0.z > 0.f ? o0.z : 0.f) * m;
  o0.w = (o0.w > 0.f ? o0.w : 0.f) * m;
  o1.x = (o1.x > 0.f ? o1.x : 0.f) * m;
  o1.y = (o1.y > 0.f ? o1.y : 0.f) * m;
  o1.z = (o1.z > 0.f ? o1.z : 0.f) * m;
  o1.w = (o1.w > 0.f ? o1.w : 0.f) * m;

  f32x4v* op = (f32x4v*)out + (size_t)row * 32 + c * 2;
  __builtin_nontemporal_store(o0, op);
  __builtin_nontemporal_store(o1, op + 1);
}

// ---------------------------------------------------------------------------
extern "C" void kernel_launch(void* const* d_in, const int* in_sizes, int n_in,
                              void* d_out, int out_size, void* d_ws,
                              size_t ws_size, hipStream_t stream) {
  const float* X = (const float*)d_in[0];     // [B,N,128]
  const int* eidx = (const int*)d_in[1];      // [B,2,E]
  const float* mask = (const float*)d_in[2];  // [B,N]
  const float* W = (const float*)d_in[3];     // [128,128]
  const float* bias = (const float*)d_in[4];  // [128]
  const float* gamma = (const float*)d_in[5];
  const float* beta = (const float*)d_in[6];
  float* out = (float*)d_out;

  // workspace (~24.3 MB)
  unsigned short* hb = (unsigned short*)d_ws;             // 16 MB bf16
  unsigned short* bucket = hb + (size_t)M_ * D_;          // 8 MB (M_*64 ushort)
  int* cnt = (int*)(bucket + (size_t)M_ * SLOTS);         // 256 KB

  // no memset needed: every cnt entry is written by its owner fill block

  gemm_fill_kernel<<<256, 1024, 0, stream>>>(X, W, bias, eidx, cnt,
                                             bucket, hb);
  gather_finalize_kernel<<<M_ / 16, 256, 0, stream>>>(hb, bucket, cnt, mask,
                                                      gamma, beta, out);
}

// Round 4
// 162.440 us; speedup vs baseline: 1.1424x; 1.0242x over previous
//
#include <hip/hip_runtime.h>

// Problem constants (fixed by reference)
#define B_ 8
#define N_ 8192
#define E_ 131072
#define D_ 128
#define M_ (B_ * N_)          // 65536 rows
#define SLOTS 64              // bucket capacity/node; P[Poisson(16)>64]~1e-21
#define FWIN 512              // nodes per fill window (one 1024-thr fill block)
#define QCAP 768              // per-wave queue entries (mean 512, +11 sigma)
constexpr float INV_SQRT_N = 0.011048543456039806f;  // 1/sqrt(8192)
constexpr float LN_EPS_C = 1e-5f;

typedef __attribute__((ext_vector_type(8))) short bf16x8;   // 8 bf16 (4 VGPRs)
typedef __attribute__((ext_vector_type(4))) float f32x4;    // MFMA C/D
typedef __attribute__((ext_vector_type(4))) float f32x4v;   // clang vec (NT ld/st)
typedef __attribute__((ext_vector_type(4))) unsigned u32x4; // 16 B gather load

static __device__ __forceinline__ unsigned short f2bf(float f) {
  unsigned u = __float_as_uint(f);
  u += 0x7fffu + ((u >> 16) & 1u);
  return (unsigned short)(u >> 16);
}
static __device__ __forceinline__ float bflo(unsigned u) {
  return __uint_as_float(u << 16);
}
static __device__ __forceinline__ float bfhi(unsigned u) {
  return __uint_as_float(u & 0xffff0000u);
}
static __device__ __forceinline__ bf16x8 cvt8v(const f32x4v a, const f32x4v b) {
  bf16x8 r;
  r[0] = (short)f2bf(a.x); r[1] = (short)f2bf(a.y);
  r[2] = (short)f2bf(a.z); r[3] = (short)f2bf(a.w);
  r[4] = (short)f2bf(b.x); r[5] = (short)f2bf(b.y);
  r[6] = (short)f2bf(b.z); r[7] = (short)f2bf(b.w);
  return r;
}
// count of set bits in m strictly below this lane
static __device__ __forceinline__ unsigned lanepos(unsigned long long m) {
  return __builtin_amdgcn_mbcnt_hi(
      (unsigned)(m >> 32), __builtin_amdgcn_mbcnt_lo((unsigned)m, 0u));
}

// ---------------------------------------------------------------------------
// K1 fused, 1024-thread blocks, exactly 256 blocks = 1 block/CU:
//   blocks 0..127   = MFMA GEMM, 512 nodes/block (16 waves).
//   blocks 128..255 = pull-based fill, 512-node window/block, 16 waves.
//
// Fill post-mortem R3: direct predicated LDS-atomic insert = 4096 sparse
// exec-masked LDS instrs/block (2048 ds_add_rtn @ ~25-30cy on the CU's single
// LDS pipe, ~25% lanes active) -> LDS-issue bound at 61us. Now: R2's ballot
// compaction at R3's occupancy. Phase A: stream TARGETS ONLY, per edge
// sub/cmp/ballot/mbcnt + one masked ds_write_b32 into a per-wave queue
// (no returning ops, no waits). Phase B: drain queue DENSELY (~512/wave ->
// 8 all-lanes-active iterations: q-read, lazy src load (L2-hot), ds_add_rtn,
// bucket write). LDS atomic instrs/block: 2048 sparse -> ~128 dense.
// Bucket staged in 64 KB LDS, coalesced writeback; format unchanged -> K2
// as-is. Fill batch = blockIdx%8 -> batch's edge slice stays XCD-L2-local.
// ---------------------------------------------------------------------------
__global__ __launch_bounds__(1024, 4) void gemm_fill_kernel(
    const float* __restrict__ X, const float* __restrict__ W,
    const float* __restrict__ bias, const int* __restrict__ eidx,
    int* __restrict__ cnt, unsigned short* __restrict__ bucket,
    unsigned short* __restrict__ hb) {
  __shared__ unsigned cnt_l[FWIN];                 // 2 KB
  __shared__ unsigned short bkt_l[FWIN * SLOTS];   // 64 KB
  __shared__ unsigned q_l[16 * QCAP];              // 48 KB per-wave queues
  if (blockIdx.x < 128) {
    const int wave = threadIdx.x >> 6;   // 0..15
    const int lane = threadIdx.x & 63;
    const int m16 = lane & 15;
    const int q = lane >> 4;
    const int hf = wave & 1;     // feature half: feats [hf*64, +64)
    const int ng = wave >> 1;    // node group: nodes [ng*64, +64)

    bf16x8 wf[4][4];  // [kt4][t]
#pragma unroll
    for (int kt4 = 0; kt4 < 4; ++kt4) {
#pragma unroll
      for (int tt = 0; tt < 4; ++tt) {
        const float* wr = W + (size_t)(hf * 64 + tt * 16 + m16) * D_ +
                          kt4 * 32 + q * 8;
        wf[kt4][tt] = cvt8v(*(const f32x4v*)wr, *(const f32x4v*)(wr + 4));
      }
    }

    const int nbase0 = blockIdx.x * 512 + ng * 64;
#pragma unroll 2
    for (int s = 0; s < 4; ++s) {
      const int nbase = nbase0 + s * 16;
      const float* xrow = X + (size_t)(nbase + m16) * D_;

      f32x4 acc[4];
#pragma unroll
      for (int tt = 0; tt < 4; ++tt) acc[tt] = (f32x4){0.f, 0.f, 0.f, 0.f};

#pragma unroll
      for (int kt4 = 0; kt4 < 4; ++kt4) {
        const f32x4v xa = __builtin_nontemporal_load(
            (const f32x4v*)(xrow + kt4 * 32 + q * 8));
        const f32x4v xb = __builtin_nontemporal_load(
            (const f32x4v*)(xrow + kt4 * 32 + q * 8 + 4));
        const bf16x8 xf = cvt8v(xa, xb);
#pragma unroll
        for (int tt = 0; tt < 4; ++tt) {
          acc[tt] = __builtin_amdgcn_mfma_f32_16x16x32_bf16(wf[kt4][tt], xf,
                                                            acc[tt], 0, 0, 0);
        }
      }

      const size_t orow = (size_t)(nbase + m16) * D_;
#pragma unroll
      for (int tt = 0; tt < 4; ++tt) {
        const int f0 = hf * 64 + tt * 16 + q * 4;
        const float4 b4 = *(const float4*)&bias[f0];
        uint2 uu;
        uu.x = (unsigned)f2bf(acc[tt][0] + b4.x) |
               ((unsigned)f2bf(acc[tt][1] + b4.y) << 16);
        uu.y = (unsigned)f2bf(acc[tt][2] + b4.z) |
               ((unsigned)f2bf(acc[tt][3] + b4.w) << 16);
        *(uint2*)(hb + orow + f0) = uu;
      }
    }
  } else {
    // ---- pull-based fill: one block = one (batch, 512-node window) ----
    const int f = blockIdx.x - 128;      // 0..127
    const int batch = f & 7;             // == blockIdx%8 -> XCD-local edges
    const int w = f >> 3;                // window 0..15
    const int t = threadIdx.x;           // 0..1023
    const int wave = t >> 6;
    const int lane = t & 63;
    const int wbase = w * FWIN;

    if (t < FWIN) cnt_l[t] = 0u;
    __syncthreads();

    const int* __restrict__ srcp = eidx + batch * 2 * E_;
    const int* __restrict__ tgtp = srcp + E_;

    unsigned* __restrict__ qw = q_l + wave * QCAP;
    unsigned qn = 0;  // wave-uniform (bumped by popc of ballot)

// one edge: compare, ballot-compact into wave queue (masked plain ds_write)
#define SCAN1(tval, eoff)                                            \
  {                                                                  \
    const unsigned l_ = (unsigned)((tval)-wbase);                    \
    const bool m_ = l_ < FWIN;                                       \
    const unsigned long long bal_ = __ballot(m_);                    \
    if (m_) qw[qn + lanepos(bal_)] = (l_ << 17) | (unsigned)(eoff);  \
    qn += (unsigned)__popcll(bal_);                                  \
  }

    // Phase A: targets only, 8 edges/thread/iter, 16 iters, 1-deep prefetch.
    int e = t * 8;
    int4 ct0 = *(const int4*)(tgtp + e);
    int4 ct1 = *(const int4*)(tgtp + e + 4);
#pragma unroll 1
    for (int it = 0; it < 15; ++it) {
      const int en = e + 8192;
      const int4 nt0 = *(const int4*)(tgtp + en);
      const int4 nt1 = *(const int4*)(tgtp + en + 4);
      SCAN1(ct0.x, e); SCAN1(ct0.y, e + 1);
      SCAN1(ct0.z, e + 2); SCAN1(ct0.w, e + 3);
      SCAN1(ct1.x, e + 4); SCAN1(ct1.y, e + 5);
      SCAN1(ct1.z, e + 6); SCAN1(ct1.w, e + 7);
      ct0 = nt0; ct1 = nt1;
      e = en;
    }
    SCAN1(ct0.x, e); SCAN1(ct0.y, e + 1);
    SCAN1(ct0.z, e + 2); SCAN1(ct0.w, e + 3);
    SCAN1(ct1.x, e + 4); SCAN1(ct1.y, e + 5);
    SCAN1(ct1.z, e + 6); SCAN1(ct1.w, e + 7);
#undef SCAN1

    // Phase B: drain own wave's queue densely; 2 independent chains in
    // flight; lazy src fetch from the XCD-L2-resident src slice.
    unsigned j = lane;
    for (; j + 64 < qn; j += 128) {
      const unsigned v0 = qw[j];
      const unsigned v1 = qw[j + 64];
      const unsigned short s0 = (unsigned short)srcp[v0 & 0x1FFFFu];
      const unsigned short s1 = (unsigned short)srcp[v1 & 0x1FFFFu];
      const unsigned p0 = atomicAdd(&cnt_l[v0 >> 17], 1u);
      const unsigned p1 = atomicAdd(&cnt_l[v1 >> 17], 1u);
      if (p0 < SLOTS) bkt_l[(v0 >> 17) * SLOTS + p0] = s0;
      if (p1 < SLOTS) bkt_l[(v1 >> 17) * SLOTS + p1] = s1;
    }
    if (j < qn) {
      const unsigned v = qw[j];
      const unsigned short s = (unsigned short)srcp[v & 0x1FFFFu];
      const unsigned p = atomicAdd(&cnt_l[v >> 17], 1u);
      if (p < SLOTS) bkt_l[(v >> 17) * SLOTS + p] = s;
    }
    __syncthreads();

    // Coalesced writeback: counts (2 KB) + bucket window (64 KB).
    const int nodebase = batch * N_ + wbase;
    if (t < FWIN) cnt[nodebase + t] = (int)cnt_l[t];
    const u32x4* ls = (const u32x4*)bkt_l;
    u32x4* gd = (u32x4*)(bucket + (size_t)nodebase * SLOTS);
#pragma unroll
    for (int i = 0; i < (FWIN * SLOTS * 2) / (16 * 1024); ++i)
      gd[i * 1024 + t] = ls[i * 1024 + t];
  }
}

// ---------------------------------------------------------------------------
// K2: gather + residual + LN + ReLU + mask (verified 16-lane-row structure).
// 4 rows/wave, 16 lanes/row, lane owns 8 feats (one u32x4 per gathered row).
// Row's 64 index slots = one 128 B line; lane c holds slots 4c..4c+3 (uint2).
// 8 independent gathers in flight per row group. XCD swizzle + NT out stores.
// ---------------------------------------------------------------------------
__global__ __launch_bounds__(256, 8) void gather_finalize_kernel(
    const unsigned short* __restrict__ hb, const unsigned short* __restrict__ bucket,
    const int* __restrict__ cnt, const float* __restrict__ mask,
    const float* __restrict__ gamma, const float* __restrict__ beta,
    float* __restrict__ out) {
  const int bid = blockIdx.x;
  const int batch = bid & 7;             // XCD-locality heuristic
  const int wave = threadIdx.x >> 6;
  const int lane = threadIdx.x & 63;
  const int g = lane >> 4;               // row within wave's 4
  const int c = lane & 15;               // 16 lanes per row
  const int r = (bid >> 3) * 16 + wave * 4 + g;  // 0..8191 within batch
  const int row = batch * N_ + r;

  const u32x4* hub4 = (const u32x4*)hb + (size_t)batch * N_ * 16;

  // independent early loads
  const int deg = min(cnt[row], SLOTS);
  const uint2 su = *(const uint2*)&bucket[(size_t)row * SLOTS + c * 4];
  const u32x4 ur = hub4[r * 16 + c];
  const float m = mask[row];

  float a[8];
#pragma unroll
  for (int k = 0; k < 8; ++k) a[k] = 0.f;

  int jb = 0;
  for (; jb + 8 <= deg; jb += 8) {
    const int L = jb >> 2;
    const unsigned w0 = (unsigned)__shfl((int)su.x, L, 16);      // jb, jb+1
    const unsigned w1 = (unsigned)__shfl((int)su.y, L, 16);      // jb+2, jb+3
    const unsigned w2 = (unsigned)__shfl((int)su.x, L + 1, 16);  // jb+4, jb+5
    const unsigned w3 = (unsigned)__shfl((int)su.y, L + 1, 16);  // jb+6, jb+7
    const int idx[8] = {(int)(w0 & 0xffff), (int)(w0 >> 16),
                        (int)(w1 & 0xffff), (int)(w1 >> 16),
                        (int)(w2 & 0xffff), (int)(w2 >> 16),
                        (int)(w3 & 0xffff), (int)(w3 >> 16)};
    u32x4 v[8];
#pragma unroll
    for (int i = 0; i < 8; ++i) v[i] = hub4[idx[i] * 16 + c];
#pragma unroll
    for (int i = 0; i < 8; ++i) {
      a[0] += bflo(v[i].x); a[1] += bfhi(v[i].x);
      a[2] += bflo(v[i].y); a[3] += bfhi(v[i].y);
      a[4] += bflo(v[i].z); a[5] += bfhi(v[i].z);
      a[6] += bflo(v[i].w); a[7] += bfhi(v[i].w);
    }
  }
  for (; jb < deg; ++jb) {
    const int L = jb >> 2;
    const unsigned w = ((jb >> 1) & 1) ? (unsigned)__shfl((int)su.y, L, 16)
                                       : (unsigned)__shfl((int)su.x, L, 16);
    const int idx = (jb & 1) ? (int)(w >> 16) : (int)(w & 0xffff);
    const u32x4 v = hub4[idx * 16 + c];
    a[0] += bflo(v.x); a[1] += bfhi(v.x);
    a[2] += bflo(v.y); a[3] += bfhi(v.y);
    a[4] += bflo(v.z); a[5] += bfhi(v.z);
    a[6] += bflo(v.w); a[7] += bfhi(v.w);
  }

  float x[8];
  x[0] = bflo(ur.x) + a[0] * INV_SQRT_N;
  x[1] = bfhi(ur.x) + a[1] * INV_SQRT_N;
  x[2] = bflo(ur.y) + a[2] * INV_SQRT_N;
  x[3] = bfhi(ur.y) + a[3] * INV_SQRT_N;
  x[4] = bflo(ur.z) + a[4] * INV_SQRT_N;
  x[5] = bfhi(ur.z) + a[5] * INV_SQRT_N;
  x[6] = bflo(ur.w) + a[6] * INV_SQRT_N;
  x[7] = bfhi(ur.w) + a[7] * INV_SQRT_N;

  float s0 = 0.f, ss = 0.f;
#pragma unroll
  for (int k = 0; k < 8; ++k) {
    s0 += x[k];
    ss += x[k] * x[k];
  }
#pragma unroll
  for (int o = 8; o >= 1; o >>= 1) {
    s0 += __shfl_xor(s0, o, 16);
    ss += __shfl_xor(ss, o, 16);
  }
  const float mu = s0 * (1.f / 128.f);
  float var = ss * (1.f / 128.f) - mu * mu;
  var = var < 0.f ? 0.f : var;
  const float rstd = rsqrtf(var + LN_EPS_C);

  const f32x4v g0 = *((const f32x4v*)gamma + c * 2);
  const f32x4v g1 = *((const f32x4v*)gamma + c * 2 + 1);
  const f32x4v b0 = *((const f32x4v*)beta + c * 2);
  const f32x4v b1 = *((const f32x4v*)beta + c * 2 + 1);

  f32x4v o0, o1;
  o0.x = (x[0] - mu) * rstd * g0.x + b0.x;
  o0.y = (x[1] - mu) * rstd * g0.y + b0.y;
  o0.z = (x[2] - mu) * rstd * g0.z + b0.z;
  o0.w = (x[3] - mu) * rstd * g0.w + b0.w;
  o1.x = (x[4] - mu) * rstd * g1.x + b1.x;
  o1.y = (x[5] - mu) * rstd * g1.y + b1.y;
  o1.z = (x[6] - mu) * rstd * g1.z + b1.z;
  o1.w = (x[7] - mu) * rstd * g1.w + b1.w;
  o0.x = (o0.x > 0.f ? o0.x : 0.f) * m;
  o0.y = (o0.y > 0.f ? o0.y : 0.f) * m;
  o0.z = (o0.z > 0.f ? o0.z : 0.f) * m;
  o0.w = (o0.w > 0.f ? o0.w : 0.f) * m;
  o1.x = (o1.x > 0.f ? o1.x : 0.f) * m;
  o1.y = (o1.y > 0.f ? o1.y : 0.f) * m;
  o1.z = (o1.z > 0.f ? o1.z : 0.f) * m;
  o1.w = (o1.w > 0.f ? o1.w : 0.f) * m;

  f32x4v* op = (f32x4v*)out + (size_t)row * 32 + c * 2;
  __builtin_nontemporal_store(o0, op);
  __builtin_nontemporal_store(o1, op + 1);
}

// ---------------------------------------------------------------------------
extern "C" void kernel_launch(void* const* d_in, const int* in_sizes, int n_in,
                              void* d_out, int out_size, void* d_ws,
                              size_t ws_size, hipStream_t stream) {
  const float* X = (const float*)d_in[0];     // [B,N,128]
  const int* eidx = (const int*)d_in[1];      // [B,2,E]
  const float* mask = (const float*)d_in[2];  // [B,N]
  const float* W = (const float*)d_in[3];     // [128,128]
  const float* bias = (const float*)d_in[4];  // [128]
  const float* gamma = (const float*)d_in[5];
  const float* beta = (const float*)d_in[6];
  float* out = (float*)d_out;

  // workspace (~24.3 MB)
  unsigned short* hb = (unsigned short*)d_ws;             // 16 MB bf16
  unsigned short* bucket = hb + (size_t)M_ * D_;          // 8 MB (M_*64 ushort)
  int* cnt = (int*)(bucket + (size_t)M_ * SLOTS);         // 256 KB

  // no memset needed: every cnt entry is written by its owner fill block

  gemm_fill_kernel<<<256, 1024, 0, stream>>>(X, W, bias, eidx, cnt,
                                             bucket, hb);
  gather_finalize_kernel<<<M_ / 16, 256, 0, stream>>>(hb, bucket, cnt, mask,
                                                      gamma, beta, out);
}

// Round 5
// 153.321 us; speedup vs baseline: 1.2103x; 1.0595x over previous
//
#include <hip/hip_runtime.h>

// Problem constants (fixed by reference)
#define B_ 8
#define N_ 8192
#define E_ 131072
#define D_ 128
#define M_ (B_ * N_)          // 65536 rows
#define SLOTS 64              // bucket capacity/node; P[Poisson(16)>64]~1e-21
#define WIN 256               // nodes per fill window (one 256-thr fill block)
#define QCAP 1280             // per-wave queue entries (mean 1024, +8 sigma)
constexpr float INV_SQRT_N = 0.011048543456039806f;  // 1/sqrt(8192)
constexpr float LN_EPS_C = 1e-5f;

typedef __attribute__((ext_vector_type(8))) short bf16x8;   // 8 bf16 (4 VGPRs)
typedef __attribute__((ext_vector_type(4))) float f32x4;    // MFMA C/D
typedef __attribute__((ext_vector_type(4))) float f32x4v;   // clang vec (NT ld/st)
typedef __attribute__((ext_vector_type(4))) unsigned u32x4; // 16 B gather load

static __device__ __forceinline__ unsigned short f2bf(float f) {
  unsigned u = __float_as_uint(f);
  u += 0x7fffu + ((u >> 16) & 1u);
  return (unsigned short)(u >> 16);
}
static __device__ __forceinline__ float bflo(unsigned u) {
  return __uint_as_float(u << 16);
}
static __device__ __forceinline__ float bfhi(unsigned u) {
  return __uint_as_float(u & 0xffff0000u);
}
static __device__ __forceinline__ bf16x8 cvt8v(const f32x4v a, const f32x4v b) {
  bf16x8 r;
  r[0] = (short)f2bf(a.x); r[1] = (short)f2bf(a.y);
  r[2] = (short)f2bf(a.z); r[3] = (short)f2bf(a.w);
  r[4] = (short)f2bf(b.x); r[5] = (short)f2bf(b.y);
  r[6] = (short)f2bf(b.z); r[7] = (short)f2bf(b.w);
  return r;
}
// count of set bits in m strictly below this lane
static __device__ __forceinline__ unsigned lanepos(unsigned long long m) {
  return __builtin_amdgcn_mbcnt_hi(
      (unsigned)(m >> 32), __builtin_amdgcn_mbcnt_lo((unsigned)m, 0u));
}

// ---------------------------------------------------------------------------
// K1 fused, 256-thread blocks, 512 blocks = 2/CU (one GEMM + one fill pair):
//   blocks 0..255   = MFMA GEMM, 256 nodes/block (R0's proven 4-wave shape).
//                     Node swizzle: block bi -> batch bi&7 (XCD bi%8), chunk
//                     bi>>3. hb rows of batch b are written ON XCD b, where
//                     K2 (batch = bid&7) re-reads them -> L2-warm gathers.
//   blocks 256..511 = pull-based fill, 256-node window (batch f&7 -> XCD f%8,
//                     edge slice + bucket stay XCD-local).
//
// Post-mortem R4: 57us with only 6.5us VALU + 0.8us MFMA work -> ~90% stall,
// ~2 lines in flight per wave (Little's law). Suspects fixed here:
// (1) launch_bounds(1024,4) capped regs at ~128 combined vs wf[4][4]=64
//     + acc + temps -> spill/remat chains. Now (256,2): 256-reg budget.
// (2) 1 block/CU homogeneous -> now GEMM+fill co-resident per CU
//     (heterogeneous pipes, 2x wave pool).
// (3) cross-XCD hb traffic for K2 -> batch-aligned swizzle everywhere.
// Fill = R4's ballot scan (no LDS-returning ops in the loop) + dense drain.
// ---------------------------------------------------------------------------
__global__ __launch_bounds__(256, 2) void gemm_fill_kernel(
    const float* __restrict__ X, const float* __restrict__ W,
    const float* __restrict__ bias, const int* __restrict__ eidx,
    int* __restrict__ cnt, unsigned short* __restrict__ bucket,
    unsigned short* __restrict__ hb) {
  __shared__ unsigned cnt_l[WIN];                 // 1 KB
  __shared__ unsigned short bkt_l[WIN * SLOTS];   // 32 KB
  __shared__ unsigned q_l[4 * QCAP];              // 20 KB per-wave queues
  if (blockIdx.x < 256) {
    const int wave = threadIdx.x >> 6;   // 0..3
    const int lane = threadIdx.x & 63;
    const int m16 = lane & 15;
    const int q = lane >> 4;
    const int hf = wave & 1;     // feature half: feats [hf*64, +64)
    const int ng = wave >> 1;    // node group: nodes [ng*128, +128)

    bf16x8 wf[4][4];  // [kt4][t]
#pragma unroll
    for (int kt4 = 0; kt4 < 4; ++kt4) {
#pragma unroll
      for (int tt = 0; tt < 4; ++tt) {
        const float* wr = W + (size_t)(hf * 64 + tt * 16 + m16) * D_ +
                          kt4 * 32 + q * 8;
        wf[kt4][tt] = cvt8v(*(const f32x4v*)wr, *(const f32x4v*)(wr + 4));
      }
    }

    const int bi = blockIdx.x;
    // batch-aligned node swizzle: batch = bi&7 runs on XCD bi%8
    const int nbase0 = (bi & 7) * N_ + (bi >> 3) * 256 + ng * 128;
#pragma unroll 2
    for (int s = 0; s < 8; ++s) {
      const int nbase = nbase0 + s * 16;
      const float* xrow = X + (size_t)(nbase + m16) * D_;

      f32x4 acc[4];
#pragma unroll
      for (int tt = 0; tt < 4; ++tt) acc[tt] = (f32x4){0.f, 0.f, 0.f, 0.f};

#pragma unroll
      for (int kt4 = 0; kt4 < 4; ++kt4) {
        const f32x4v xa = __builtin_nontemporal_load(
            (const f32x4v*)(xrow + kt4 * 32 + q * 8));
        const f32x4v xb = __builtin_nontemporal_load(
            (const f32x4v*)(xrow + kt4 * 32 + q * 8 + 4));
        const bf16x8 xf = cvt8v(xa, xb);
#pragma unroll
        for (int tt = 0; tt < 4; ++tt) {
          acc[tt] = __builtin_amdgcn_mfma_f32_16x16x32_bf16(wf[kt4][tt], xf,
                                                            acc[tt], 0, 0, 0);
        }
      }

      const size_t orow = (size_t)(nbase + m16) * D_;
#pragma unroll
      for (int tt = 0; tt < 4; ++tt) {
        const int f0 = hf * 64 + tt * 16 + q * 4;
        const float4 b4 = *(const float4*)&bias[f0];
        uint2 uu;
        uu.x = (unsigned)f2bf(acc[tt][0] + b4.x) |
               ((unsigned)f2bf(acc[tt][1] + b4.y) << 16);
        uu.y = (unsigned)f2bf(acc[tt][2] + b4.z) |
               ((unsigned)f2bf(acc[tt][3] + b4.w) << 16);
        *(uint2*)(hb + orow + f0) = uu;
      }
    }
  } else {
    // ---- pull-based fill: one block = one (batch, 256-node window) ----
    const int f = blockIdx.x - 256;      // 0..255
    const int batch = f & 7;             // XCD-local edge slice & bucket
    const int w = f >> 3;                // window 0..31
    const int t = threadIdx.x;           // 0..255
    const int wave = t >> 6;
    const int lane = t & 63;
    const int wbase = w * WIN;

    cnt_l[t] = 0u;
    __syncthreads();

    const int* __restrict__ srcp = eidx + batch * 2 * E_;
    const int* __restrict__ tgtp = srcp + E_;

    unsigned* __restrict__ qw = q_l + wave * QCAP;
    unsigned qn = 0;  // wave-uniform (bumped by popc of ballot)

// one edge: compare, ballot-compact into wave queue (masked plain ds_write)
#define SCAN1(tval, eoff)                                            \
  {                                                                  \
    const unsigned l_ = (unsigned)((tval)-wbase);                    \
    const bool m_ = l_ < WIN;                                        \
    const unsigned long long bal_ = __ballot(m_);                    \
    if (m_) qw[qn + lanepos(bal_)] = (l_ << 17) | (unsigned)(eoff);  \
    qn += (unsigned)__popcll(bal_);                                  \
  }

    // Phase A: targets only, 8 edges/thread/iter, 64 iters, 1-deep prefetch.
    int e = t * 8;
    int4 ct0 = *(const int4*)(tgtp + e);
    int4 ct1 = *(const int4*)(tgtp + e + 4);
#pragma unroll 1
    for (int it = 0; it < 63; ++it) {
      const int en = e + 2048;
      const int4 nt0 = *(const int4*)(tgtp + en);
      const int4 nt1 = *(const int4*)(tgtp + en + 4);
      SCAN1(ct0.x, e); SCAN1(ct0.y, e + 1);
      SCAN1(ct0.z, e + 2); SCAN1(ct0.w, e + 3);
      SCAN1(ct1.x, e + 4); SCAN1(ct1.y, e + 5);
      SCAN1(ct1.z, e + 6); SCAN1(ct1.w, e + 7);
      ct0 = nt0; ct1 = nt1;
      e = en;
    }
    SCAN1(ct0.x, e); SCAN1(ct0.y, e + 1);
    SCAN1(ct0.z, e + 2); SCAN1(ct0.w, e + 3);
    SCAN1(ct1.x, e + 4); SCAN1(ct1.y, e + 5);
    SCAN1(ct1.z, e + 6); SCAN1(ct1.w, e + 7);
#undef SCAN1

    // Phase B: drain own wave's queue densely; 2 independent chains in
    // flight; lazy src fetch from the XCD-L2-resident src slice.
    unsigned j = lane;
    for (; j + 64 < qn; j += 128) {
      const unsigned v0 = qw[j];
      const unsigned v1 = qw[j + 64];
      const unsigned short s0 = (unsigned short)srcp[v0 & 0x1FFFFu];
      const unsigned short s1 = (unsigned short)srcp[v1 & 0x1FFFFu];
      const unsigned p0 = atomicAdd(&cnt_l[v0 >> 17], 1u);
      const unsigned p1 = atomicAdd(&cnt_l[v1 >> 17], 1u);
      if (p0 < SLOTS) bkt_l[(v0 >> 17) * SLOTS + p0] = s0;
      if (p1 < SLOTS) bkt_l[(v1 >> 17) * SLOTS + p1] = s1;
    }
    if (j < qn) {
      const unsigned v = qw[j];
      const unsigned short s = (unsigned short)srcp[v & 0x1FFFFu];
      const unsigned p = atomicAdd(&cnt_l[v >> 17], 1u);
      if (p < SLOTS) bkt_l[(v >> 17) * SLOTS + p] = s;
    }
    __syncthreads();

    // Coalesced writeback: counts (1 KB) + bucket window (32 KB).
    const int nodebase = batch * N_ + wbase;
    cnt[nodebase + t] = (int)cnt_l[t];
    const u32x4* ls = (const u32x4*)bkt_l;
    u32x4* gd = (u32x4*)(bucket + (size_t)nodebase * SLOTS);
#pragma unroll
    for (int i = 0; i < (WIN * SLOTS * 2) / (16 * 256); ++i)
      gd[i * 256 + t] = ls[i * 256 + t];
  }
}

// ---------------------------------------------------------------------------
// K2: gather + residual + LN + ReLU + mask (verified 16-lane-row structure).
// 4 rows/wave, 16 lanes/row, lane owns 8 feats (one u32x4 per gathered row).
// Row's 64 index slots = one 128 B line; lane c holds slots 4c..4c+3 (uint2).
// batch = bid&7 matches K1's writers -> hb/bucket reads are XCD-L2-warm.
// ---------------------------------------------------------------------------
__global__ __launch_bounds__(256, 8) void gather_finalize_kernel(
    const unsigned short* __restrict__ hb, const unsigned short* __restrict__ bucket,
    const int* __restrict__ cnt, const float* __restrict__ mask,
    const float* __restrict__ gamma, const float* __restrict__ beta,
    float* __restrict__ out) {
  const int bid = blockIdx.x;
  const int batch = bid & 7;             // XCD-locality (matches K1 writers)
  const int wave = threadIdx.x >> 6;
  const int lane = threadIdx.x & 63;
  const int g = lane >> 4;               // row within wave's 4
  const int c = lane & 15;               // 16 lanes per row
  const int r = (bid >> 3) * 16 + wave * 4 + g;  // 0..8191 within batch
  const int row = batch * N_ + r;

  const u32x4* hub4 = (const u32x4*)hb + (size_t)batch * N_ * 16;

  // independent early loads
  const int deg = min(cnt[row], SLOTS);
  const uint2 su = *(const uint2*)&bucket[(size_t)row * SLOTS + c * 4];
  const u32x4 ur = hub4[r * 16 + c];
  const float m = mask[row];

  float a[8];
#pragma unroll
  for (int k = 0; k < 8; ++k) a[k] = 0.f;

  int jb = 0;
  for (; jb + 8 <= deg; jb += 8) {
    const int L = jb >> 2;
    const unsigned w0 = (unsigned)__shfl((int)su.x, L, 16);      // jb, jb+1
    const unsigned w1 = (unsigned)__shfl((int)su.y, L, 16);      // jb+2, jb+3
    const unsigned w2 = (unsigned)__shfl((int)su.x, L + 1, 16);  // jb+4, jb+5
    const unsigned w3 = (unsigned)__shfl((int)su.y, L + 1, 16);  // jb+6, jb+7
    const int idx[8] = {(int)(w0 & 0xffff), (int)(w0 >> 16),
                        (int)(w1 & 0xffff), (int)(w1 >> 16),
                        (int)(w2 & 0xffff), (int)(w2 >> 16),
                        (int)(w3 & 0xffff), (int)(w3 >> 16)};
    u32x4 v[8];
#pragma unroll
    for (int i = 0; i < 8; ++i) v[i] = hub4[idx[i] * 16 + c];
#pragma unroll
    for (int i = 0; i < 8; ++i) {
      a[0] += bflo(v[i].x); a[1] += bfhi(v[i].x);
      a[2] += bflo(v[i].y); a[3] += bfhi(v[i].y);
      a[4] += bflo(v[i].z); a[5] += bfhi(v[i].z);
      a[6] += bflo(v[i].w); a[7] += bfhi(v[i].w);
    }
  }
  for (; jb < deg; ++jb) {
    const int L = jb >> 2;
    const unsigned w = ((jb >> 1) & 1) ? (unsigned)__shfl((int)su.y, L, 16)
                                       : (unsigned)__shfl((int)su.x, L, 16);
    const int idx = (jb & 1) ? (int)(w >> 16) : (int)(w & 0xffff);
    const u32x4 v = hub4[idx * 16 + c];
    a[0] += bflo(v.x); a[1] += bfhi(v.x);
    a[2] += bflo(v.y); a[3] += bfhi(v.y);
    a[4] += bflo(v.z); a[5] += bfhi(v.z);
    a[6] += bflo(v.w); a[7] += bfhi(v.w);
  }

  float x[8];
  x[0] = bflo(ur.x) + a[0] * INV_SQRT_N;
  x[1] = bfhi(ur.x) + a[1] * INV_SQRT_N;
  x[2] = bflo(ur.y) + a[2] * INV_SQRT_N;
  x[3] = bfhi(ur.y) + a[3] * INV_SQRT_N;
  x[4] = bflo(ur.z) + a[4] * INV_SQRT_N;
  x[5] = bfhi(ur.z) + a[5] * INV_SQRT_N;
  x[6] = bflo(ur.w) + a[6] * INV_SQRT_N;
  x[7] = bfhi(ur.w) + a[7] * INV_SQRT_N;

  float s0 = 0.f, ss = 0.f;
#pragma unroll
  for (int k = 0; k < 8; ++k) {
    s0 += x[k];
    ss += x[k] * x[k];
  }
#pragma unroll
  for (int o = 8; o >= 1; o >>= 1) {
    s0 += __shfl_xor(s0, o, 16);
    ss += __shfl_xor(ss, o, 16);
  }
  const float mu = s0 * (1.f / 128.f);
  float var = ss * (1.f / 128.f) - mu * mu;
  var = var < 0.f ? 0.f : var;
  const float rstd = rsqrtf(var + LN_EPS_C);

  const f32x4v g0 = *((const f32x4v*)gamma + c * 2);
  const f32x4v g1 = *((const f32x4v*)gamma + c * 2 + 1);
  const f32x4v b0 = *((const f32x4v*)beta + c * 2);
  const f32x4v b1 = *((const f32x4v*)beta + c * 2 + 1);

  f32x4v o0, o1;
  o0.x = (x[0] - mu) * rstd * g0.x + b0.x;
  o0.y = (x[1] - mu) * rstd * g0.y + b0.y;
  o0.z = (x[2] - mu) * rstd * g0.z + b0.z;
  o0.w = (x[3] - mu) * rstd * g0.w + b0.w;
  o1.x = (x[4] - mu) * rstd * g1.x + b1.x;
  o1.y = (x[5] - mu) * rstd * g1.y + b1.y;
  o1.z = (x[6] - mu) * rstd * g1.z + b1.z;
  o1.w = (x[7] - mu) * rstd * g1.w + b1.w;
  o0.x = (o0.x > 0.f ? o0.x : 0.f) * m;
  o0.y = (o0.y > 0.f ? o0.y : 0.f) * m;
  o0.z = (o0.z > 0.f ? o0.z : 0.f) * m;
  o0.w = (o0.w > 0.f ? o0.w : 0.f) * m;
  o1.x = (o1.x > 0.f ? o1.x : 0.f) * m;
  o1.y = (o1.y > 0.f ? o1.y : 0.f) * m;
  o1.z = (o1.z > 0.f ? o1.z : 0.f) * m;
  o1.w = (o1.w > 0.f ? o1.w : 0.f) * m;

  f32x4v* op = (f32x4v*)out + (size_t)row * 32 + c * 2;
  __builtin_nontemporal_store(o0, op);
  __builtin_nontemporal_store(o1, op + 1);
}

// ---------------------------------------------------------------------------
extern "C" void kernel_launch(void* const* d_in, const int* in_sizes, int n_in,
                              void* d_out, int out_size, void* d_ws,
                              size_t ws_size, hipStream_t stream) {
  const float* X = (const float*)d_in[0];     // [B,N,128]
  const int* eidx = (const int*)d_in[1];      // [B,2,E]
  const float* mask = (const float*)d_in[2];  // [B,N]
  const float* W = (const float*)d_in[3];     // [128,128]
  const float* bias = (const float*)d_in[4];  // [128]
  const float* gamma = (const float*)d_in[5];
  const float* beta = (const float*)d_in[6];
  float* out = (float*)d_out;

  // workspace (~24.3 MB)
  unsigned short* hb = (unsigned short*)d_ws;             // 16 MB bf16
  unsigned short* bucket = hb + (size_t)M_ * D_;          // 8 MB (M_*64 ushort)
  int* cnt = (int*)(bucket + (size_t)M_ * SLOTS);         // 256 KB

  // no memset needed: every cnt entry is written by its owner fill block

  gemm_fill_kernel<<<512, 256, 0, stream>>>(X, W, bias, eidx, cnt,
                                            bucket, hb);
  gather_finalize_kernel<<<M_ / 16, 256, 0, stream>>>(hb, bucket, cnt, mask,
                                                      gamma, beta, out);
}

// Round 6
// 147.024 us; speedup vs baseline: 1.2622x; 1.0428x over previous
//
#include <hip/hip_runtime.h>

// Problem constants (fixed by reference)
#define B_ 8
#define N_ 8192
#define E_ 131072
#define D_ 128
#define M_ (B_ * N_)          // 65536 rows
#define SLOTS 64              // bucket capacity/node; P[Poisson(16)>64]~1e-21
#define NCH 32                // chunks per batch (counting sort)
#define CHE (E_ / NCH)        // 4096 edges per chunk
constexpr float INV_SQRT_N = 0.011048543456039806f;  // 1/sqrt(8192)
constexpr float LN_EPS_C = 1e-5f;

typedef __attribute__((ext_vector_type(8))) short bf16x8;   // 8 bf16 (4 VGPRs)
typedef __attribute__((ext_vector_type(4))) float f32x4;    // MFMA C/D
typedef __attribute__((ext_vector_type(4))) float f32x4v;   // clang vec (NT ld/st)
typedef __attribute__((ext_vector_type(4))) unsigned u32x4; // 16 B gather load

static __device__ __forceinline__ unsigned short f2bf(float f) {
  unsigned u = __float_as_uint(f);
  u += 0x7fffu + ((u >> 16) & 1u);
  return (unsigned short)(u >> 16);
}
static __device__ __forceinline__ float bflo(unsigned u) {
  return __uint_as_float(u << 16);
}
static __device__ __forceinline__ float bfhi(unsigned u) {
  return __uint_as_float(u & 0xffff0000u);
}
static __device__ __forceinline__ bf16x8 cvt8v(const f32x4v a, const f32x4v b) {
  bf16x8 r;
  r[0] = (short)f2bf(a.x); r[1] = (short)f2bf(a.y);
  r[2] = (short)f2bf(a.z); r[3] = (short)f2bf(a.w);
  r[4] = (short)f2bf(b.x); r[5] = (short)f2bf(b.y);
  r[6] = (short)f2bf(b.z); r[7] = (short)f2bf(b.w);
  return r;
}

// ---------------------------------------------------------------------------
// Bucket fill post-mortem R1-R5: every "rescan the edge list per window"
// variant (predicated atomics, ballot compaction, 1-16 waves/block) landed
// 55-93us while all analytical models said ~10us; R4 (4 waves/SIMD) == R5
// (1 wave/SIMD) proves it was never latency-hiding. The invariant was the
// rescan structure itself (per-edge exec-mask/ballot bookkeeping, 32x read
// amplification). Replaced this round by a 3-phase COUNTING SORT where every
// instruction is dense (all 64 lanes useful, no ballots, no masked LDS ops):
//   K1 blocks 256..511: count  - LDS histogram of 4096-edge chunk, dense
//                                ds_add; dump ushort counts to histc.
//   prefix_kernel:               per (batch,node): exclusive prefix over the
//                                32 chunk counts -> chunk base table + cnt.
//   place_kernel:                re-stream chunk edges; rank = dense
//                                ds_add_rtn on LDS hist; slot = base+rank;
//                                scatter 2B store (fire-and-forget).
// histc (4 MB) is overlaid on `out`, which K2 fully overwrites afterwards.
// Chunks own disjoint slot ranges per node -> race-free. Bucket/cnt format
// unchanged -> K2 untouched. All block->batch maps keep batch==blockIdx%8
// so edge slices / hb / bucket stay XCD-L2-local end to end.
// ---------------------------------------------------------------------------
__global__ __launch_bounds__(256, 2) void gemm_count_kernel(
    const float* __restrict__ X, const float* __restrict__ W,
    const float* __restrict__ bias, const int* __restrict__ eidx,
    unsigned short* __restrict__ histc, unsigned short* __restrict__ hb) {
  __shared__ unsigned hist[N_];   // 32 KB
  if (blockIdx.x < 256) {
    // ---- MFMA GEMM, 256 nodes/block (proven R5 structure) ----
    const int wave = threadIdx.x >> 6;   // 0..3
    const int lane = threadIdx.x & 63;
    const int m16 = lane & 15;
    const int q = lane >> 4;
    const int hf = wave & 1;     // feature half: feats [hf*64, +64)
    const int ng = wave >> 1;    // node group: nodes [ng*128, +128)

    bf16x8 wf[4][4];  // [kt4][t]
#pragma unroll
    for (int kt4 = 0; kt4 < 4; ++kt4) {
#pragma unroll
      for (int tt = 0; tt < 4; ++tt) {
        const float* wr = W + (size_t)(hf * 64 + tt * 16 + m16) * D_ +
                          kt4 * 32 + q * 8;
        wf[kt4][tt] = cvt8v(*(const f32x4v*)wr, *(const f32x4v*)(wr + 4));
      }
    }

    const int bi = blockIdx.x;
    // batch-aligned node swizzle: batch = bi&7 runs on XCD bi%8
    const int nbase0 = (bi & 7) * N_ + (bi >> 3) * 256 + ng * 128;
#pragma unroll 2
    for (int s = 0; s < 8; ++s) {
      const int nbase = nbase0 + s * 16;
      const float* xrow = X + (size_t)(nbase + m16) * D_;

      f32x4 acc[4];
#pragma unroll
      for (int tt = 0; tt < 4; ++tt) acc[tt] = (f32x4){0.f, 0.f, 0.f, 0.f};

#pragma unroll
      for (int kt4 = 0; kt4 < 4; ++kt4) {
        const f32x4v xa = __builtin_nontemporal_load(
            (const f32x4v*)(xrow + kt4 * 32 + q * 8));
        const f32x4v xb = __builtin_nontemporal_load(
            (const f32x4v*)(xrow + kt4 * 32 + q * 8 + 4));
        const bf16x8 xf = cvt8v(xa, xb);
#pragma unroll
        for (int tt = 0; tt < 4; ++tt) {
          acc[tt] = __builtin_amdgcn_mfma_f32_16x16x32_bf16(wf[kt4][tt], xf,
                                                            acc[tt], 0, 0, 0);
        }
      }

      const size_t orow = (size_t)(nbase + m16) * D_;
#pragma unroll
      for (int tt = 0; tt < 4; ++tt) {
        const int f0 = hf * 64 + tt * 16 + q * 4;
        const float4 b4 = *(const float4*)&bias[f0];
        uint2 uu;
        uu.x = (unsigned)f2bf(acc[tt][0] + b4.x) |
               ((unsigned)f2bf(acc[tt][1] + b4.y) << 16);
        uu.y = (unsigned)f2bf(acc[tt][2] + b4.z) |
               ((unsigned)f2bf(acc[tt][3] + b4.w) << 16);
        *(uint2*)(hb + orow + f0) = uu;
      }
    }
  } else {
    // ---- count: block = (batch b, chunk c of 4096 edges) ----
    const int f = blockIdx.x - 256;   // 0..255
    const int b = f & 7;              // XCD-local edge slice
    const int c = f >> 3;             // 0..31
    const int t = threadIdx.x;

#pragma unroll
    for (int i = 0; i < N_ / 256; ++i) hist[t + i * 256] = 0u;
    __syncthreads();

    const int* __restrict__ tgtp = eidx + b * 2 * E_ + E_ + c * CHE;
    // 16 edges/thread, dense LDS histogram adds (all 64 lanes active)
#pragma unroll
    for (int k = 0; k < 4; ++k) {
      const int4 tv = *(const int4*)(tgtp + t * 16 + k * 4);
      atomicAdd(&hist[tv.x], 1u);
      atomicAdd(&hist[tv.y], 1u);
      atomicAdd(&hist[tv.z], 1u);
      atomicAdd(&hist[tv.w], 1u);
    }
    __syncthreads();

    // dump counts as ushort pairs (coalesced u32 stores)
    unsigned* dst = (unsigned*)(histc + ((size_t)b * NCH + c) * N_);
#pragma unroll
    for (int i = 0; i < N_ / 512; ++i) {
      const int j = t + i * 256;               // u32 index 0..4095
      const unsigned lo = hist[2 * j];
      const unsigned hi = hist[2 * j + 1];
      dst[j] = (lo & 0xffffu) | (hi << 16);
    }
  }
}

// ---------------------------------------------------------------------------
// prefix: thread = (batch b, node n). Exclusive prefix of the 32 chunk
// counts -> rewrite histc in place as chunk bases; total -> cnt.
// blockIdx&7 == b keeps reads on the XCD that wrote them.
// ---------------------------------------------------------------------------
__global__ __launch_bounds__(256, 8) void prefix_kernel(
    unsigned short* __restrict__ histc, int* __restrict__ cnt) {
  const int b = blockIdx.x & 7;
  const int nb = blockIdx.x >> 3;            // 0..31
  const int n = nb * 256 + threadIdx.x;      // 0..8191
  unsigned short* base = histc + (size_t)b * NCH * N_ + n;
  unsigned short v[NCH];
#pragma unroll
  for (int c = 0; c < NCH; ++c) v[c] = base[(size_t)c * N_];
  unsigned run = 0;
#pragma unroll
  for (int c = 0; c < NCH; ++c) {
    const unsigned x = v[c];
    base[(size_t)c * N_] = (unsigned short)run;
    run += x;
  }
  cnt[b * N_ + n] = (int)run;
}

// ---------------------------------------------------------------------------
// place: block = (batch b, chunk c). Re-stream the chunk's (tgt,src); rank
// via dense ds_add_rtn on a fresh LDS histogram (unique within chunk+node);
// slot = chunk base + rank (disjoint ranges across chunks -> race-free);
// scatter 2 B store into the bucket (fire-and-forget, no round trip).
// ---------------------------------------------------------------------------
__global__ __launch_bounds__(256, 2) void place_kernel(
    const int* __restrict__ eidx, const unsigned short* __restrict__ histc,
    unsigned short* __restrict__ bucket) {
  __shared__ unsigned hist[N_];   // 32 KB
  const int b = blockIdx.x & 7;
  const int c = blockIdx.x >> 3;  // 0..31
  const int t = threadIdx.x;

#pragma unroll
  for (int i = 0; i < N_ / 256; ++i) hist[t + i * 256] = 0u;
  __syncthreads();

  const int* __restrict__ srcp = eidx + b * 2 * E_ + c * CHE;
  const int* __restrict__ tgtp = srcp + E_;
  const unsigned short* __restrict__ basep = histc + ((size_t)b * NCH + c) * N_;
  unsigned short* __restrict__ bkt = bucket + (size_t)b * N_ * SLOTS;

#pragma unroll
  for (int k = 0; k < 4; ++k) {
    const int4 tv = *(const int4*)(tgtp + t * 16 + k * 4);
    const int4 sv = *(const int4*)(srcp + t * 16 + k * 4);
    // independent base gathers (L2-hot 16 KB slice) + dense rank atomics
    const unsigned b0 = basep[tv.x];
    const unsigned b1 = basep[tv.y];
    const unsigned b2 = basep[tv.z];
    const unsigned b3 = basep[tv.w];
    const unsigned p0 = atomicAdd(&hist[tv.x], 1u) + b0;
    const unsigned p1 = atomicAdd(&hist[tv.y], 1u) + b1;
    const unsigned p2 = atomicAdd(&hist[tv.z], 1u) + b2;
    const unsigned p3 = atomicAdd(&hist[tv.w], 1u) + b3;
    if (p0 < SLOTS) bkt[(size_t)tv.x * SLOTS + p0] = (unsigned short)sv.x;
    if (p1 < SLOTS) bkt[(size_t)tv.y * SLOTS + p1] = (unsigned short)sv.y;
    if (p2 < SLOTS) bkt[(size_t)tv.z * SLOTS + p2] = (unsigned short)sv.z;
    if (p3 < SLOTS) bkt[(size_t)tv.w * SLOTS + p3] = (unsigned short)sv.w;
  }
}

// ---------------------------------------------------------------------------
// K2: gather + residual + LN + ReLU + mask (verified 16-lane-row structure).
// 4 rows/wave, 16 lanes/row, lane owns 8 feats (one u32x4 per gathered row).
// Row's 64 index slots = one 128 B line; lane c holds slots 4c..4c+3 (uint2).
// batch = bid&7 matches K1's writers -> hb/bucket reads are XCD-L2-warm.
// ---------------------------------------------------------------------------
__global__ __launch_bounds__(256, 8) void gather_finalize_kernel(
    const unsigned short* __restrict__ hb, const unsigned short* __restrict__ bucket,
    const int* __restrict__ cnt, const float* __restrict__ mask,
    const float* __restrict__ gamma, const float* __restrict__ beta,
    float* __restrict__ out) {
  const int bid = blockIdx.x;
  const int batch = bid & 7;             // XCD-locality (matches K1 writers)
  const int wave = threadIdx.x >> 6;
  const int lane = threadIdx.x & 63;
  const int g = lane >> 4;               // row within wave's 4
  const int c = lane & 15;               // 16 lanes per row
  const int r = (bid >> 3) * 16 + wave * 4 + g;  // 0..8191 within batch
  const int row = batch * N_ + r;

  const u32x4* hub4 = (const u32x4*)hb + (size_t)batch * N_ * 16;

  // independent early loads
  const int deg = min(cnt[row], SLOTS);
  const uint2 su = *(const uint2*)&bucket[(size_t)row * SLOTS + c * 4];
  const u32x4 ur = hub4[r * 16 + c];
  const float m = mask[row];

  float a[8];
#pragma unroll
  for (int k = 0; k < 8; ++k) a[k] = 0.f;

  int jb = 0;
  for (; jb + 8 <= deg; jb += 8) {
    const int L = jb >> 2;
    const unsigned w0 = (unsigned)__shfl((int)su.x, L, 16);      // jb, jb+1
    const unsigned w1 = (unsigned)__shfl((int)su.y, L, 16);      // jb+2, jb+3
    const unsigned w2 = (unsigned)__shfl((int)su.x, L + 1, 16);  // jb+4, jb+5
    const unsigned w3 = (unsigned)__shfl((int)su.y, L + 1, 16);  // jb+6, jb+7
    const int idx[8] = {(int)(w0 & 0xffff), (int)(w0 >> 16),
                        (int)(w1 & 0xffff), (int)(w1 >> 16),
                        (int)(w2 & 0xffff), (int)(w2 >> 16),
                        (int)(w3 & 0xffff), (int)(w3 >> 16)};
    u32x4 v[8];
#pragma unroll
    for (int i = 0; i < 8; ++i) v[i] = hub4[idx[i] * 16 + c];
#pragma unroll
    for (int i = 0; i < 8; ++i) {
      a[0] += bflo(v[i].x); a[1] += bfhi(v[i].x);
      a[2] += bflo(v[i].y); a[3] += bfhi(v[i].y);
      a[4] += bflo(v[i].z); a[5] += bfhi(v[i].z);
      a[6] += bflo(v[i].w); a[7] += bfhi(v[i].w);
    }
  }
  for (; jb < deg; ++jb) {
    const int L = jb >> 2;
    const unsigned w = ((jb >> 1) & 1) ? (unsigned)__shfl((int)su.y, L, 16)
                                       : (unsigned)__shfl((int)su.x, L, 16);
    const int idx = (jb & 1) ? (int)(w >> 16) : (int)(w & 0xffff);
    const u32x4 v = hub4[idx * 16 + c];
    a[0] += bflo(v.x); a[1] += bfhi(v.x);
    a[2] += bflo(v.y); a[3] += bfhi(v.y);
    a[4] += bflo(v.z); a[5] += bfhi(v.z);
    a[6] += bflo(v.w); a[7] += bfhi(v.w);
  }

  float x[8];
  x[0] = bflo(ur.x) + a[0] * INV_SQRT_N;
  x[1] = bfhi(ur.x) + a[1] * INV_SQRT_N;
  x[2] = bflo(ur.y) + a[2] * INV_SQRT_N;
  x[3] = bfhi(ur.y) + a[3] * INV_SQRT_N;
  x[4] = bflo(ur.z) + a[4] * INV_SQRT_N;
  x[5] = bfhi(ur.z) + a[5] * INV_SQRT_N;
  x[6] = bflo(ur.w) + a[6] * INV_SQRT_N;
  x[7] = bfhi(ur.w) + a[7] * INV_SQRT_N;

  float s0 = 0.f, ss = 0.f;
#pragma unroll
  for (int k = 0; k < 8; ++k) {
    s0 += x[k];
    ss += x[k] * x[k];
  }
#pragma unroll
  for (int o = 8; o >= 1; o >>= 1) {
    s0 += __shfl_xor(s0, o, 16);
    ss += __shfl_xor(ss, o, 16);
  }
  const float mu = s0 * (1.f / 128.f);
  float var = ss * (1.f / 128.f) - mu * mu;
  var = var < 0.f ? 0.f : var;
  const float rstd = rsqrtf(var + LN_EPS_C);

  const f32x4v g0 = *((const f32x4v*)gamma + c * 2);
  const f32x4v g1 = *((const f32x4v*)gamma + c * 2 + 1);
  const f32x4v b0 = *((const f32x4v*)beta + c * 2);
  const f32x4v b1 = *((const f32x4v*)beta + c * 2 + 1);

  f32x4v o0, o1;
  o0.x = (x[0] - mu) * rstd * g0.x + b0.x;
  o0.y = (x[1] - mu) * rstd * g0.y + b0.y;
  o0.z = (x[2] - mu) * rstd * g0.z + b0.z;
  o0.w = (x[3] - mu) * rstd * g0.w + b0.w;
  o1.x = (x[4] - mu) * rstd * g1.x + b1.x;
  o1.y = (x[5] - mu) * rstd * g1.y + b1.y;
  o1.z = (x[6] - mu) * rstd * g1.z + b1.z;
  o1.w = (x[7] - mu) * rstd * g1.w + b1.w;
  o0.x = (o0.x > 0.f ? o0.x : 0.f) * m;
  o0.y = (o0.y > 0.f ? o0.y : 0.f) * m;
  o0.z = (o0.z > 0.f ? o0.z : 0.f) * m;
  o0.w = (o0.w > 0.f ? o0.w : 0.f) * m;
  o1.x = (o1.x > 0.f ? o1.x : 0.f) * m;
  o1.y = (o1.y > 0.f ? o1.y : 0.f) * m;
  o1.z = (o1.z > 0.f ? o1.z : 0.f) * m;
  o1.w = (o1.w > 0.f ? o1.w : 0.f) * m;

  f32x4v* op = (f32x4v*)out + (size_t)row * 32 + c * 2;
  __builtin_nontemporal_store(o0, op);
  __builtin_nontemporal_store(o1, op + 1);
}

// ---------------------------------------------------------------------------
extern "C" void kernel_launch(void* const* d_in, const int* in_sizes, int n_in,
                              void* d_out, int out_size, void* d_ws,
                              size_t ws_size, hipStream_t stream) {
  const float* X = (const float*)d_in[0];     // [B,N,128]
  const int* eidx = (const int*)d_in[1];      // [B,2,E]
  const float* mask = (const float*)d_in[2];  // [B,N]
  const float* W = (const float*)d_in[3];     // [128,128]
  const float* bias = (const float*)d_in[4];  // [128]
  const float* gamma = (const float*)d_in[5];
  const float* beta = (const float*)d_in[6];
  float* out = (float*)d_out;

  // workspace (~24.3 MB)
  unsigned short* hb = (unsigned short*)d_ws;             // 16 MB bf16
  unsigned short* bucket = hb + (size_t)M_ * D_;          // 8 MB (M_*64 ushort)
  int* cnt = (int*)(bucket + (size_t)M_ * SLOTS);         // 256 KB
  // chunk count/base table (4 MB) overlaid on `out` — K2 overwrites all of
  // `out` afterwards, so this costs zero workspace.
  unsigned short* histc = (unsigned short*)out;           // [8][32][8192]

  gemm_count_kernel<<<512, 256, 0, stream>>>(X, W, bias, eidx, histc, hb);
  prefix_kernel<<<256, 256, 0, stream>>>(histc, cnt);
  place_kernel<<<256, 256, 0, stream>>>(eidx, histc, bucket);
  gather_finalize_kernel<<<M_ / 16, 256, 0, stream>>>(hb, bucket, cnt, mask,
                                                      gamma, beta, out);
}